// Round 6
// baseline (544.125 us; speedup 1.0000x reference)
//
#include <hip/hip_runtime.h>
#include <hip/hip_bf16.h>

// N=50000 nodes, R<=16 relations, H=64 hidden, L=32 labels, E=1.6M edges
// Zero-global-atomic pipeline:
//   p1_hist/p1_scan/p1_scatter: MSD partition of edges by dst>>7 (391 buckets),
//     per-block LDS histograms + precomputed per-block bases (LDS cursors only)
//   p2_sort: one workgroup per bucket, 128-bin LDS counting sort on dst&127,
//     emits esort=(rel<<20)|src grouped by dst + coalesced start[d]/deg[d]
//   layer1_gather: wave/dst; per-(r,d) counts via 16 wave ballots (writes invtT
//     for layer2); 8 independent w1-row loads per group; converged shfls only
//   zgemm: z[n, r*32+l] = x[n,:] @ w2[r]  (bf16)
//   layer2_gather: wave/dst; 8 edges in flight; fused root2 matvec + sigmoid

#define BKT_BITS 7
#define BKT_SIZE 128
#define NB1 512

__global__ void p1_hist(const int* __restrict__ dst, int* __restrict__ gh,
                        int E, int C, int nbkt) {
    __shared__ int h[512];
    int t = threadIdx.x;
    for (int i = t; i < nbkt; i += 256) h[i] = 0;
    __syncthreads();
    int b = blockIdx.x;
    int lo = b * C, hi = min(E, lo + C);
    for (int i = lo + t; i < hi; i += 256) atomicAdd(&h[dst[i] >> BKT_BITS], 1);
    __syncthreads();
    for (int i = t; i < nbkt; i += 256) gh[b * nbkt + i] = h[i];
}

// single block, 512 threads: bucketStart[g] = exscan(totals); gb[b][g] = running base
__global__ void p1_scan(const int* __restrict__ gh, int* __restrict__ gb,
                        int* __restrict__ bucketStart, int nb1, int nbkt) {
    __shared__ int totals[512];
    int g = threadIdx.x;
    if (g < nbkt) {
        int acc = 0;
        for (int b = 0; b < nb1; ++b) acc += gh[b * nbkt + g];
        totals[g] = acc;
    }
    __syncthreads();
    if (g == 0) {
        int run = 0;
        for (int i = 0; i < nbkt; ++i) { int v = totals[i]; totals[i] = run; run += v; }
    }
    __syncthreads();
    if (g < nbkt) {
        bucketStart[g] = totals[g];
        int run = totals[g];
        for (int b = 0; b < nb1; ++b) { gb[b * nbkt + g] = run; run += gh[b * nbkt + g]; }
    }
}

__global__ void p1_scatter(const int* __restrict__ src, const int* __restrict__ dst,
                           const int* __restrict__ et, const int* __restrict__ gb,
                           int* __restrict__ keyB, int* __restrict__ payB,
                           int E, int C, int nbkt) {
    __shared__ int cur[512];
    int t = threadIdx.x;
    int b = blockIdx.x;
    for (int i = t; i < nbkt; i += 256) cur[i] = gb[b * nbkt + i];
    __syncthreads();
    int lo = b * C, hi = min(E, lo + C);
    for (int i = lo + t; i < hi; i += 256) {
        int d = dst[i];
        int p = atomicAdd(&cur[d >> BKT_BITS], 1);   // LDS atomic only
        keyB[p] = d;
        payB[p] = (et[i] << 20) | src[i];
    }
}

// one workgroup per bucket: counting sort on dst&127; coalesced start/deg output
__global__ __launch_bounds__(256) void p2_sort(
        const int* __restrict__ keyB, const int* __restrict__ payB,
        const int* __restrict__ bucketStart, int* __restrict__ esort,
        int* __restrict__ start, int* __restrict__ deg, int N, int E, int nbkt) {
    int g = blockIdx.x;
    int lo = bucketStart[g];
    int hi = (g + 1 < nbkt) ? bucketStart[g + 1] : E;
    int n = hi - lo;
    __shared__ int hist[BKT_SIZE], base[BKT_SIZE], cur[BKT_SIZE];
    int t = threadIdx.x;
    if (t < BKT_SIZE) hist[t] = 0;
    __syncthreads();
    for (int i = t; i < n; i += 256) atomicAdd(&hist[keyB[lo + i] & (BKT_SIZE - 1)], 1);
    __syncthreads();
    if (t == 0) {
        int run = 0;
        for (int i = 0; i < BKT_SIZE; ++i) { base[i] = run; run += hist[i]; }
    }
    __syncthreads();
    if (t < BKT_SIZE) {
        cur[t] = base[t];
        int d = g * BKT_SIZE + t;
        if (d < N) { start[d] = lo + base[t]; deg[d] = hist[t]; }
    }
    __syncthreads();
    for (int i = t; i < n; i += 256) {
        int d = keyB[lo + i];
        int p = atomicAdd(&cur[d & (BKT_SIZE - 1)], 1);   // LDS atomic only
        esort[lo + p] = payB[lo + i];
    }
}

// Wave per dst, lane = h. Counts per (r,d) via 16 ballots (writes invtT for L2),
// then accumulates 8 independent w1-row loads per group. All shfls converged.
__global__ __launch_bounds__(256) void layer1_gather(
        const int* __restrict__ esort, const int* __restrict__ start,
        const int* __restrict__ deg, float* __restrict__ invtT,
        const float* __restrict__ w1, const float* __restrict__ root1,
        const float* __restrict__ bias1, float* __restrict__ x, int N) {
    int lane = threadIdx.x & 63;
    int myr = lane & 15;
    int wave = (blockIdx.x * blockDim.x + threadIdx.x) >> 6;
    int nwaves = (gridDim.x * blockDim.x) >> 6;
    for (int d = wave; d < N; d += nwaves) {
        int beg = start[d];
        int dg = deg[d];
        // count sweep: c = |{e in segment : rel_e == myr}|
        int c = 0;
        for (int i = 0; i < dg; i += 64) {
            int idx = i + lane;
            int v = esort[beg + min(idx, dg - 1)];
            int rel = v >> 20;
            bool valid = idx < dg;
#pragma unroll
            for (int rr = 0; rr < 16; ++rr) {
                unsigned long long m = __ballot(valid && (rel == rr));
                if (myr == rr) c += __popcll(m);
            }
        }
        float invc = (c > 0) ? 1.0f / (float)c : 0.0f;
        if (lane < 16) invtT[(size_t)d * 16 + lane] = invc;
        // accumulate sweep
        float acc0 = 0.f, acc1 = 0.f, acc2 = 0.f, acc3 = 0.f;
        float acc4 = 0.f, acc5 = 0.f, acc6 = 0.f, acc7 = 0.f;
        for (int i = 0; i < dg; i += 64) {
            int v = esort[beg + min(i + lane, dg - 1)];
            int lim = min(64, dg - i);                    // wave-uniform
            for (int j = 0; j < lim; j += 8) {
                int c0 = __shfl(v, min(j + 0, lim - 1), 64);
                int c1 = __shfl(v, min(j + 1, lim - 1), 64);
                int c2 = __shfl(v, min(j + 2, lim - 1), 64);
                int c3 = __shfl(v, min(j + 3, lim - 1), 64);
                int c4 = __shfl(v, min(j + 4, lim - 1), 64);
                int c5 = __shfl(v, min(j + 5, lim - 1), 64);
                int c6 = __shfl(v, min(j + 6, lim - 1), 64);
                int c7 = __shfl(v, min(j + 7, lim - 1), 64);
                float w0 = w1[((size_t)(c0 >> 20) * N + (c0 & 0xFFFFF)) * 64 + lane];
                float w1v = w1[((size_t)(c1 >> 20) * N + (c1 & 0xFFFFF)) * 64 + lane];
                float w2v = w1[((size_t)(c2 >> 20) * N + (c2 & 0xFFFFF)) * 64 + lane];
                float w3 = w1[((size_t)(c3 >> 20) * N + (c3 & 0xFFFFF)) * 64 + lane];
                float w4 = w1[((size_t)(c4 >> 20) * N + (c4 & 0xFFFFF)) * 64 + lane];
                float w5 = w1[((size_t)(c5 >> 20) * N + (c5 & 0xFFFFF)) * 64 + lane];
                float w6 = w1[((size_t)(c6 >> 20) * N + (c6 & 0xFFFFF)) * 64 + lane];
                float w7 = w1[((size_t)(c7 >> 20) * N + (c7 & 0xFFFFF)) * 64 + lane];
                float f0 = __shfl(invc, c0 >> 20, 64) * ((j + 0 < lim) ? 1.f : 0.f);
                float f1 = __shfl(invc, c1 >> 20, 64) * ((j + 1 < lim) ? 1.f : 0.f);
                float f2 = __shfl(invc, c2 >> 20, 64) * ((j + 2 < lim) ? 1.f : 0.f);
                float f3 = __shfl(invc, c3 >> 20, 64) * ((j + 3 < lim) ? 1.f : 0.f);
                float f4 = __shfl(invc, c4 >> 20, 64) * ((j + 4 < lim) ? 1.f : 0.f);
                float f5 = __shfl(invc, c5 >> 20, 64) * ((j + 5 < lim) ? 1.f : 0.f);
                float f6 = __shfl(invc, c6 >> 20, 64) * ((j + 6 < lim) ? 1.f : 0.f);
                float f7 = __shfl(invc, c7 >> 20, 64) * ((j + 7 < lim) ? 1.f : 0.f);
                acc0 += w0 * f0;  acc1 += w1v * f1;
                acc2 += w2v * f2; acc3 += w3 * f3;
                acc4 += w4 * f4;  acc5 += w5 * f5;
                acc6 += w6 * f6;  acc7 += w7 * f7;
            }
        }
        float acc = ((acc0 + acc1) + (acc2 + acc3)) + ((acc4 + acc5) + (acc6 + acc7));
        float val = acc + root1[(size_t)d * 64 + lane] + bias1[lane];
        x[(size_t)d * 64 + lane] = val > 0.f ? val : 0.f;
    }
}

// z[n, r*32+l] = sum_h x[n,h] * w2[r,h,l], stored bf16.
__global__ void zgemm_kernel(const float* __restrict__ x, const float* __restrict__ w2,
                             __hip_bfloat16* __restrict__ z, int N) {
    __shared__ float xs[64];
    int t = threadIdx.x;          // 256 threads; cols t and t+256 of 512
    int o0 = t, o1 = t + 256;
    float wc0[64], wc1[64];
    {
        const float* w0  = w2 + (size_t)(o0 >> 5) * 64 * 32 + (o0 & 31);
        const float* w1p = w2 + (size_t)(o1 >> 5) * 64 * 32 + (o1 & 31);
#pragma unroll
        for (int h = 0; h < 64; ++h) {
            wc0[h] = w0[h * 32];
            wc1[h] = w1p[h * 32];
        }
    }
    for (int n = blockIdx.x; n < N; n += gridDim.x) {
        __syncthreads();
        if (t < 64) xs[t] = x[(size_t)n * 64 + t];
        __syncthreads();
        float a0 = 0.0f, a1 = 0.0f;
#pragma unroll
        for (int h = 0; h < 64; ++h) {
            float xv = xs[h];
            a0 += xv * wc0[h];
            a1 += xv * wc1[h];
        }
        z[(size_t)n * 512 + o0] = __float2bfloat16(a0);
        z[(size_t)n * 512 + o1] = __float2bfloat16(a1);
    }
}

// Wave per dst; lane = sub*32 + l. 8 edges in flight per group.
__global__ __launch_bounds__(256) void layer2_gather(
        const int* __restrict__ esort, const int* __restrict__ start,
        const int* __restrict__ deg, const float* __restrict__ invtT,
        const __hip_bfloat16* __restrict__ z, const float* __restrict__ x,
        const float* __restrict__ root2, const float* __restrict__ bias2,
        float* __restrict__ out, int N) {
    int lane = threadIdx.x & 63;
    int sub = lane >> 5;
    int l = lane & 31;
    int wave = (blockIdx.x * blockDim.x + threadIdx.x) >> 6;
    int nwaves = (gridDim.x * blockDim.x) >> 6;
    for (int d = wave; d < N; d += nwaves) {
        int beg = start[d];
        int dg = deg[d];
        float invc = invtT[(size_t)d * 16 + (lane & 15)];
        float xr = x[(size_t)d * 64 + lane];
        float acc0 = 0.f, acc1 = 0.f, acc2 = 0.f, acc3 = 0.f;
        for (int i = 0; i < dg; i += 64) {
            int v = esort[beg + min(i + lane, dg - 1)];
            int lim = min(64, dg - i);                    // wave-uniform
            for (int j = 0; j < lim; j += 8) {
                int c0 = __shfl(v, min(j + 0 + sub, lim - 1), 64);
                int c1 = __shfl(v, min(j + 2 + sub, lim - 1), 64);
                int c2 = __shfl(v, min(j + 4 + sub, lim - 1), 64);
                int c3 = __shfl(v, min(j + 6 + sub, lim - 1), 64);
                float z0 = __bfloat162float(z[((size_t)(c0 & 0xFFFFF) * 16 + (c0 >> 20)) * 32 + l]);
                float z1 = __bfloat162float(z[((size_t)(c1 & 0xFFFFF) * 16 + (c1 >> 20)) * 32 + l]);
                float z2 = __bfloat162float(z[((size_t)(c2 & 0xFFFFF) * 16 + (c2 >> 20)) * 32 + l]);
                float z3 = __bfloat162float(z[((size_t)(c3 & 0xFFFFF) * 16 + (c3 >> 20)) * 32 + l]);
                float f0 = __shfl(invc, c0 >> 20, 64) * ((j + 0 + sub < lim) ? 1.f : 0.f);
                float f1 = __shfl(invc, c1 >> 20, 64) * ((j + 2 + sub < lim) ? 1.f : 0.f);
                float f2 = __shfl(invc, c2 >> 20, 64) * ((j + 4 + sub < lim) ? 1.f : 0.f);
                float f3 = __shfl(invc, c3 >> 20, 64) * ((j + 6 + sub < lim) ? 1.f : 0.f);
                acc0 += z0 * f0;
                acc1 += z1 * f1;
                acc2 += z2 * f2;
                acc3 += z3 * f3;
            }
        }
        float acc = (acc0 + acc1) + (acc2 + acc3);
        float rt = 0.f;
#pragma unroll
        for (int h2 = 0; h2 < 32; ++h2) {
            int h = sub * 32 + h2;
            rt += __shfl(xr, h, 64) * root2[h * 32 + l];
        }
        float tot = acc + rt;
        tot += __shfl_xor(tot, 32, 64);               // combine sub halves
        float logit = tot + bias2[l];
        if (sub == 0) out[(size_t)d * 32 + l] = 1.0f / (1.0f + __expf(-logit));
    }
}

// ---------------- fallback path (small workspace): round-2 verified atomics ----
__global__ void count_kernel(const int* __restrict__ dst, const int* __restrict__ et,
                             int* __restrict__ cnt, int E, int N) {
    int i = blockIdx.x * blockDim.x + threadIdx.x;
    int stride = gridDim.x * blockDim.x;
    for (; i < E; i += stride) atomicAdd(&cnt[et[i] * N + dst[i]], 1);
}
__global__ void layer1_kernel(const int* __restrict__ src, const int* __restrict__ dst,
                              const int* __restrict__ et, const int* __restrict__ cnt,
                              const float* __restrict__ w1, float* __restrict__ h1,
                              int E, int N) {
    int lane = threadIdx.x & 63;
    int wave = (blockIdx.x * blockDim.x + threadIdx.x) >> 6;
    int nwaves = (gridDim.x * blockDim.x) >> 6;
    for (int e = wave; e < E; e += nwaves) {
        int r = et[e], s = src[e], d = dst[e];
        float inv = 1.0f / (float)cnt[r * N + d];
        atomicAdd(&h1[(size_t)d * 64 + lane], w1[((size_t)r * N + s) * 64 + lane] * inv);
    }
}
__global__ void x_kernel(float* __restrict__ h1, const float* __restrict__ root1,
                         const float* __restrict__ bias1, int NH) {
    int i = blockIdx.x * blockDim.x + threadIdx.x;
    int stride = gridDim.x * blockDim.x;
    for (; i < NH; i += stride) {
        float v = h1[i] + root1[i] + bias1[i & 63];
        h1[i] = v > 0.0f ? v : 0.0f;
    }
}
__global__ void layer2_kernel(const int* __restrict__ src, const int* __restrict__ dst,
                              const int* __restrict__ et, const int* __restrict__ cnt,
                              const float* __restrict__ x, const float* __restrict__ w2,
                              float* __restrict__ out, int E, int N) {
    int lane = threadIdx.x & 63;
    int l = lane & 31;
    int half = lane >> 5;
    int wave = (blockIdx.x * blockDim.x + threadIdx.x) >> 6;
    int nwaves = (gridDim.x * blockDim.x) >> 6;
    for (int e = wave; e < E; e += nwaves) {
        int r = et[e], s = src[e], d = dst[e];
        float inv = 1.0f / (float)cnt[r * N + d];
        float xv = x[(size_t)s * 64 + lane];
        const float* w2r = w2 + ((size_t)r * 64 + half * 32) * 32 + l;
        float acc = 0.0f;
#pragma unroll
        for (int i2 = 0; i2 < 32; ++i2) acc += __shfl(xv, half * 32 + i2, 64) * w2r[(size_t)i2 * 32];
        acc += __shfl_xor(acc, 32, 64);
        if (half == 0) atomicAdd(&out[(size_t)d * 32 + l], acc * inv);
    }
}
__global__ void final_kernel(float* __restrict__ out, const float* __restrict__ x,
                             const float* __restrict__ root2, const float* __restrict__ bias2,
                             int N) {
    int idx = blockIdx.x * blockDim.x + threadIdx.x;
    int stride = gridDim.x * blockDim.x;
    int total = N * 32;
    for (; idx < total; idx += stride) {
        int n = idx >> 5, l = idx & 31;
        float acc = out[idx] + bias2[l];
        const float* xr = x + (size_t)n * 64;
#pragma unroll
        for (int h = 0; h < 64; ++h) acc += xr[h] * root2[h * 32 + l];
        out[idx] = 1.0f / (1.0f + __expf(-acc));
    }
}

extern "C" void kernel_launch(void* const* d_in, const int* in_sizes, int n_in,
                              void* d_out, int out_size, void* d_ws, size_t ws_size,
                              hipStream_t stream) {
    const int*   edge_index = (const int*)d_in[0];   // [2, E]
    const int*   edge_type  = (const int*)d_in[1];   // [E]
    const float* w1         = (const float*)d_in[2]; // [R, N, 64]
    const float* root1      = (const float*)d_in[3]; // [N, 64]
    const float* bias1      = (const float*)d_in[4]; // [64]
    const float* w2         = (const float*)d_in[5]; // [R, 64, 32]
    const float* root2      = (const float*)d_in[6]; // [64, 32]
    const float* bias2      = (const float*)d_in[7]; // [32]
    float* out = (float*)d_out;

    int E = in_sizes[1];
    int H = in_sizes[4];            // 64
    int L = in_sizes[7];            // 32
    int N = in_sizes[3] / H;
    int R = in_sizes[5] / (H * L);  // <= 16

    const int* src = edge_index;
    const int* dst = edge_index + E;

    int nbkt = (N + BKT_SIZE - 1) / BKT_SIZE;   // 391 for N=50000
    int C = (E + NB1 - 1) / NB1;                // edges per phase-1 block

    // ws layout: [gh NB1*nbkt][gb NB1*nbkt][bucketStart nbkt][keyB E][payB E]
    //            [esort E][invtT N*16 f32][start N][deg N][x N*64 f32][z N*16*32 bf16]
    size_t off_gh    = 0;
    size_t off_gb    = off_gh + (size_t)NB1 * nbkt * 4;
    size_t off_bs    = off_gb + (size_t)NB1 * nbkt * 4;
    size_t off_keyB  = off_bs + (size_t)nbkt * 4 + 64;
    size_t off_payB  = off_keyB + (size_t)E * 4;
    size_t off_esort = off_payB + (size_t)E * 4;
    size_t off_invt  = off_esort + (size_t)E * 4;
    size_t off_start = off_invt + (size_t)N * 16 * 4;
    size_t off_deg   = off_start + (size_t)N * 4;
    size_t off_x     = off_deg + (size_t)N * 4;
    size_t off_z     = off_x + (size_t)N * H * 4;
    size_t need      = off_z + (size_t)N * 16 * L * 2;

    char* ws = (char*)d_ws;
    if (ws_size >= need && R <= 16 && nbkt <= 512 && N < (1 << 20)) {
        int*   gh    = (int*)(ws + off_gh);
        int*   gb    = (int*)(ws + off_gb);
        int*   bs    = (int*)(ws + off_bs);
        int*   keyB  = (int*)(ws + off_keyB);
        int*   payB  = (int*)(ws + off_payB);
        int*   esort = (int*)(ws + off_esort);
        float* invtT = (float*)(ws + off_invt);
        int*   start = (int*)(ws + off_start);
        int*   deg   = (int*)(ws + off_deg);
        float* x     = (float*)(ws + off_x);
        __hip_bfloat16* z = (__hip_bfloat16*)(ws + off_z);

        p1_hist      <<<NB1, 256, 0, stream>>>(dst, gh, E, C, nbkt);
        p1_scan      <<<1, 512, 0, stream>>>(gh, gb, bs, NB1, nbkt);
        p1_scatter   <<<NB1, 256, 0, stream>>>(src, dst, edge_type, gb, keyB, payB, E, C, nbkt);
        p2_sort      <<<nbkt, 256, 0, stream>>>(keyB, payB, bs, esort, start, deg, N, E, nbkt);
        layer1_gather<<<(N + 3) / 4, 256, 0, stream>>>(esort, start, deg, invtT, w1, root1, bias1, x, N);
        zgemm_kernel <<<2048, 256, 0, stream>>>(x, w2, z, N);
        layer2_gather<<<(N + 3) / 4, 256, 0, stream>>>(esort, start, deg, invtT, z, x, root2, bias2, out, N);
    } else {
        // fallback: round-2 verified atomic path (needs ~16 MB)
        size_t cnt_bytes = (size_t)R * N * sizeof(int);
        int*   cnt = (int*)ws;
        float* h1  = (float*)(ws + cnt_bytes);
        hipMemsetAsync(cnt, 0, cnt_bytes + (size_t)N * H * sizeof(float), stream);
        hipMemsetAsync(out, 0, (size_t)N * L * sizeof(float), stream);
        count_kernel <<<2048, 256, 0, stream>>>(dst, edge_type, cnt, E, N);
        layer1_kernel<<<4096, 256, 0, stream>>>(src, dst, edge_type, cnt, w1, h1, E, N);
        x_kernel     <<<2048, 256, 0, stream>>>(h1, root1, bias1, N * H);
        layer2_kernel<<<4096, 256, 0, stream>>>(src, dst, edge_type, cnt, h1, w2, out, E, N);
        final_kernel <<<2048, 256, 0, stream>>>(out, h1, root2, bias2, N);
    }
}

// Round 7
// 325.149 us; speedup vs baseline: 1.6735x; 1.6735x over previous
//
#include <hip/hip_runtime.h>
#include <hip/hip_bf16.h>

// N=50000 nodes, R<=16 relations, H=64 hidden, L=32 labels, E=1.6M edges
// Zero-global-atomic pipeline, parallel scan:
//   p1_hist: per-block LDS histogram of dst>>7 -> gh[g][b]  (transposed)
//   scan_a:  391 blocks; block g scans gh[g][0..NB1) -> gb local prefixes + totals[g]
//   scan_b:  1 block; exclusive scan totals -> bucketStart
//   p1_scatter: packed code (dst&127)<<24|et<<20|src -> payB (single array)
//   p2_sort: one wg/bucket, 128-bin LDS counting sort, emits esort+start+deg
//   layer1_gather: wave/dst; ballot counts -> invtT; 8 w1-row loads in flight
//   zgemm: z[n, r*32+l] = x[n,:] @ w2[r]  (bf16)
//   layer2_gather: wave/dst; 8 edges in flight; fused root2 matvec + sigmoid

#define BKT_BITS 7
#define BKT_SIZE 128
#define NB1 512

__global__ void p1_hist(const int* __restrict__ dst, int* __restrict__ gh,
                        int E, int C, int nbkt) {
    __shared__ int h[512];
    int t = threadIdx.x;
    for (int i = t; i < nbkt; i += 256) h[i] = 0;
    __syncthreads();
    int b = blockIdx.x;
    int lo = b * C, hi = min(E, lo + C);
    for (int i = lo + t; i < hi; i += 256) atomicAdd(&h[dst[i] >> BKT_BITS], 1);
    __syncthreads();
    for (int i = t; i < nbkt; i += 256) gh[(size_t)i * NB1 + b] = h[i];
}

// block g: Hillis-Steele scan over gh[g][0..NB1) -> gb[g][b]=exclusive, totals[g]
__global__ __launch_bounds__(NB1) void scan_a(const int* __restrict__ gh,
                                              int* __restrict__ gb,
                                              int* __restrict__ totals) {
    __shared__ int buf[NB1];
    int g = blockIdx.x;
    int t = threadIdx.x;
    int v = gh[(size_t)g * NB1 + t];
    buf[t] = v;
    __syncthreads();
    for (int off = 1; off < NB1; off <<= 1) {
        int tmp = (t >= off) ? buf[t - off] : 0;
        __syncthreads();
        buf[t] += tmp;
        __syncthreads();
    }
    gb[(size_t)g * NB1 + t] = buf[t] - v;     // exclusive prefix
    if (t == NB1 - 1) totals[g] = buf[t];
}

// single block: exclusive scan of totals[0..nbkt) -> bucketStart
__global__ __launch_bounds__(512) void scan_b(const int* __restrict__ totals,
                                              int* __restrict__ bucketStart, int nbkt) {
    __shared__ int buf[512];
    int t = threadIdx.x;
    int v = (t < nbkt) ? totals[t] : 0;
    buf[t] = v;
    __syncthreads();
    for (int off = 1; off < 512; off <<= 1) {
        int tmp = (t >= off) ? buf[t - off] : 0;
        __syncthreads();
        buf[t] += tmp;
        __syncthreads();
    }
    if (t < nbkt) bucketStart[t] = buf[t] - v;
}

__global__ void p1_scatter(const int* __restrict__ src, const int* __restrict__ dst,
                           const int* __restrict__ et, const int* __restrict__ gb,
                           const int* __restrict__ bucketStart,
                           int* __restrict__ payB, int E, int C, int nbkt) {
    __shared__ int cur[512];
    int t = threadIdx.x;
    int b = blockIdx.x;
    for (int i = t; i < nbkt; i += 256) cur[i] = bucketStart[i] + gb[(size_t)i * NB1 + b];
    __syncthreads();
    int lo = b * C, hi = min(E, lo + C);
    for (int i = lo + t; i < hi; i += 256) {
        int d = dst[i];
        int p = atomicAdd(&cur[d >> BKT_BITS], 1);   // LDS atomic only
        payB[p] = ((d & (BKT_SIZE - 1)) << 24) | (et[i] << 20) | src[i];
    }
}

// one workgroup per bucket: counting sort on packed bin bits; coalesced start/deg
__global__ __launch_bounds__(256) void p2_sort(
        const int* __restrict__ payB, const int* __restrict__ bucketStart,
        int* __restrict__ esort, int* __restrict__ start, int* __restrict__ deg,
        int N, int E, int nbkt) {
    int g = blockIdx.x;
    int lo = bucketStart[g];
    int hi = (g + 1 < nbkt) ? bucketStart[g + 1] : E;
    int n = hi - lo;
    __shared__ int hist[BKT_SIZE], base[BKT_SIZE], cur[BKT_SIZE];
    int t = threadIdx.x;
    if (t < BKT_SIZE) hist[t] = 0;
    __syncthreads();
    for (int i = t; i < n; i += 256) atomicAdd(&hist[(payB[lo + i] >> 24) & (BKT_SIZE - 1)], 1);
    __syncthreads();
    if (t == 0) {
        int run = 0;
        for (int i = 0; i < BKT_SIZE; ++i) { base[i] = run; run += hist[i]; }
    }
    __syncthreads();
    if (t < BKT_SIZE) {
        cur[t] = base[t];
        int d = g * BKT_SIZE + t;
        if (d < N) { start[d] = lo + base[t]; deg[d] = hist[t]; }
    }
    __syncthreads();
    for (int i = t; i < n; i += 256) {
        int v = payB[lo + i];
        int p = atomicAdd(&cur[(v >> 24) & (BKT_SIZE - 1)], 1);   // LDS atomic only
        esort[lo + p] = v & 0x00FFFFFF;    // (et<<20)|src
    }
}

// Wave per dst, lane = h. Counts per (r,d) via 16 ballots (writes invtT for L2),
// then accumulates 8 independent w1-row loads per group. All shfls converged.
__global__ __launch_bounds__(256) void layer1_gather(
        const int* __restrict__ esort, const int* __restrict__ start,
        const int* __restrict__ deg, float* __restrict__ invtT,
        const float* __restrict__ w1, const float* __restrict__ root1,
        const float* __restrict__ bias1, float* __restrict__ x, int N) {
    int lane = threadIdx.x & 63;
    int myr = lane & 15;
    int wave = (blockIdx.x * blockDim.x + threadIdx.x) >> 6;
    int nwaves = (gridDim.x * blockDim.x) >> 6;
    for (int d = wave; d < N; d += nwaves) {
        int beg = start[d];
        int dg = deg[d];
        int c = 0;
        for (int i = 0; i < dg; i += 64) {
            int idx = i + lane;
            int v = esort[beg + min(idx, dg - 1)];
            int rel = v >> 20;
            bool valid = idx < dg;
#pragma unroll
            for (int rr = 0; rr < 16; ++rr) {
                unsigned long long m = __ballot(valid && (rel == rr));
                if (myr == rr) c += __popcll(m);
            }
        }
        float invc = (c > 0) ? 1.0f / (float)c : 0.0f;
        if (lane < 16) invtT[(size_t)d * 16 + lane] = invc;
        float acc0 = 0.f, acc1 = 0.f, acc2 = 0.f, acc3 = 0.f;
        float acc4 = 0.f, acc5 = 0.f, acc6 = 0.f, acc7 = 0.f;
        for (int i = 0; i < dg; i += 64) {
            int v = esort[beg + min(i + lane, dg - 1)];
            int lim = min(64, dg - i);                    // wave-uniform
            for (int j = 0; j < lim; j += 8) {
                int c0 = __shfl(v, min(j + 0, lim - 1), 64);
                int c1 = __shfl(v, min(j + 1, lim - 1), 64);
                int c2 = __shfl(v, min(j + 2, lim - 1), 64);
                int c3 = __shfl(v, min(j + 3, lim - 1), 64);
                int c4 = __shfl(v, min(j + 4, lim - 1), 64);
                int c5 = __shfl(v, min(j + 5, lim - 1), 64);
                int c6 = __shfl(v, min(j + 6, lim - 1), 64);
                int c7 = __shfl(v, min(j + 7, lim - 1), 64);
                float w0 = w1[((size_t)(c0 >> 20) * N + (c0 & 0xFFFFF)) * 64 + lane];
                float w1v = w1[((size_t)(c1 >> 20) * N + (c1 & 0xFFFFF)) * 64 + lane];
                float w2v = w1[((size_t)(c2 >> 20) * N + (c2 & 0xFFFFF)) * 64 + lane];
                float w3 = w1[((size_t)(c3 >> 20) * N + (c3 & 0xFFFFF)) * 64 + lane];
                float w4 = w1[((size_t)(c4 >> 20) * N + (c4 & 0xFFFFF)) * 64 + lane];
                float w5 = w1[((size_t)(c5 >> 20) * N + (c5 & 0xFFFFF)) * 64 + lane];
                float w6 = w1[((size_t)(c6 >> 20) * N + (c6 & 0xFFFFF)) * 64 + lane];
                float w7 = w1[((size_t)(c7 >> 20) * N + (c7 & 0xFFFFF)) * 64 + lane];
                float f0 = __shfl(invc, c0 >> 20, 64) * ((j + 0 < lim) ? 1.f : 0.f);
                float f1 = __shfl(invc, c1 >> 20, 64) * ((j + 1 < lim) ? 1.f : 0.f);
                float f2 = __shfl(invc, c2 >> 20, 64) * ((j + 2 < lim) ? 1.f : 0.f);
                float f3 = __shfl(invc, c3 >> 20, 64) * ((j + 3 < lim) ? 1.f : 0.f);
                float f4 = __shfl(invc, c4 >> 20, 64) * ((j + 4 < lim) ? 1.f : 0.f);
                float f5 = __shfl(invc, c5 >> 20, 64) * ((j + 5 < lim) ? 1.f : 0.f);
                float f6 = __shfl(invc, c6 >> 20, 64) * ((j + 6 < lim) ? 1.f : 0.f);
                float f7 = __shfl(invc, c7 >> 20, 64) * ((j + 7 < lim) ? 1.f : 0.f);
                acc0 += w0 * f0;  acc1 += w1v * f1;
                acc2 += w2v * f2; acc3 += w3 * f3;
                acc4 += w4 * f4;  acc5 += w5 * f5;
                acc6 += w6 * f6;  acc7 += w7 * f7;
            }
        }
        float acc = ((acc0 + acc1) + (acc2 + acc3)) + ((acc4 + acc5) + (acc6 + acc7));
        float val = acc + root1[(size_t)d * 64 + lane] + bias1[lane];
        x[(size_t)d * 64 + lane] = val > 0.f ? val : 0.f;
    }
}

// z[n, r*32+l] = sum_h x[n,h] * w2[r,h,l], stored bf16.
__global__ void zgemm_kernel(const float* __restrict__ x, const float* __restrict__ w2,
                             __hip_bfloat16* __restrict__ z, int N) {
    __shared__ float xs[64];
    int t = threadIdx.x;          // 256 threads; cols t and t+256 of 512
    int o0 = t, o1 = t + 256;
    float wc0[64], wc1[64];
    {
        const float* w0  = w2 + (size_t)(o0 >> 5) * 64 * 32 + (o0 & 31);
        const float* w1p = w2 + (size_t)(o1 >> 5) * 64 * 32 + (o1 & 31);
#pragma unroll
        for (int h = 0; h < 64; ++h) {
            wc0[h] = w0[h * 32];
            wc1[h] = w1p[h * 32];
        }
    }
    for (int n = blockIdx.x; n < N; n += gridDim.x) {
        __syncthreads();
        if (t < 64) xs[t] = x[(size_t)n * 64 + t];
        __syncthreads();
        float a0 = 0.0f, a1 = 0.0f;
#pragma unroll
        for (int h = 0; h < 64; ++h) {
            float xv = xs[h];
            a0 += xv * wc0[h];
            a1 += xv * wc1[h];
        }
        z[(size_t)n * 512 + o0] = __float2bfloat16(a0);
        z[(size_t)n * 512 + o1] = __float2bfloat16(a1);
    }
}

// Wave per dst; lane = sub*32 + l. 8 edges in flight per group.
__global__ __launch_bounds__(256) void layer2_gather(
        const int* __restrict__ esort, const int* __restrict__ start,
        const int* __restrict__ deg, const float* __restrict__ invtT,
        const __hip_bfloat16* __restrict__ z, const float* __restrict__ x,
        const float* __restrict__ root2, const float* __restrict__ bias2,
        float* __restrict__ out, int N) {
    int lane = threadIdx.x & 63;
    int sub = lane >> 5;
    int l = lane & 31;
    int wave = (blockIdx.x * blockDim.x + threadIdx.x) >> 6;
    int nwaves = (gridDim.x * blockDim.x) >> 6;
    for (int d = wave; d < N; d += nwaves) {
        int beg = start[d];
        int dg = deg[d];
        float invc = invtT[(size_t)d * 16 + (lane & 15)];
        float xr = x[(size_t)d * 64 + lane];
        float acc0 = 0.f, acc1 = 0.f, acc2 = 0.f, acc3 = 0.f;
        for (int i = 0; i < dg; i += 64) {
            int v = esort[beg + min(i + lane, dg - 1)];
            int lim = min(64, dg - i);                    // wave-uniform
            for (int j = 0; j < lim; j += 8) {
                int c0 = __shfl(v, min(j + 0 + sub, lim - 1), 64);
                int c1 = __shfl(v, min(j + 2 + sub, lim - 1), 64);
                int c2 = __shfl(v, min(j + 4 + sub, lim - 1), 64);
                int c3 = __shfl(v, min(j + 6 + sub, lim - 1), 64);
                float z0 = __bfloat162float(z[((size_t)(c0 & 0xFFFFF) * 16 + (c0 >> 20)) * 32 + l]);
                float z1 = __bfloat162float(z[((size_t)(c1 & 0xFFFFF) * 16 + (c1 >> 20)) * 32 + l]);
                float z2 = __bfloat162float(z[((size_t)(c2 & 0xFFFFF) * 16 + (c2 >> 20)) * 32 + l]);
                float z3 = __bfloat162float(z[((size_t)(c3 & 0xFFFFF) * 16 + (c3 >> 20)) * 32 + l]);
                float f0 = __shfl(invc, c0 >> 20, 64) * ((j + 0 + sub < lim) ? 1.f : 0.f);
                float f1 = __shfl(invc, c1 >> 20, 64) * ((j + 2 + sub < lim) ? 1.f : 0.f);
                float f2 = __shfl(invc, c2 >> 20, 64) * ((j + 4 + sub < lim) ? 1.f : 0.f);
                float f3 = __shfl(invc, c3 >> 20, 64) * ((j + 6 + sub < lim) ? 1.f : 0.f);
                acc0 += z0 * f0;
                acc1 += z1 * f1;
                acc2 += z2 * f2;
                acc3 += z3 * f3;
            }
        }
        float acc = (acc0 + acc1) + (acc2 + acc3);
        float rt = 0.f;
#pragma unroll
        for (int h2 = 0; h2 < 32; ++h2) {
            int h = sub * 32 + h2;
            rt += __shfl(xr, h, 64) * root2[h * 32 + l];
        }
        float tot = acc + rt;
        tot += __shfl_xor(tot, 32, 64);               // combine sub halves
        float logit = tot + bias2[l];
        if (sub == 0) out[(size_t)d * 32 + l] = 1.0f / (1.0f + __expf(-logit));
    }
}

// ---------------- fallback path (small workspace): round-2 verified atomics ----
__global__ void count_kernel(const int* __restrict__ dst, const int* __restrict__ et,
                             int* __restrict__ cnt, int E, int N) {
    int i = blockIdx.x * blockDim.x + threadIdx.x;
    int stride = gridDim.x * blockDim.x;
    for (; i < E; i += stride) atomicAdd(&cnt[et[i] * N + dst[i]], 1);
}
__global__ void layer1_kernel(const int* __restrict__ src, const int* __restrict__ dst,
                              const int* __restrict__ et, const int* __restrict__ cnt,
                              const float* __restrict__ w1, float* __restrict__ h1,
                              int E, int N) {
    int lane = threadIdx.x & 63;
    int wave = (blockIdx.x * blockDim.x + threadIdx.x) >> 6;
    int nwaves = (gridDim.x * blockDim.x) >> 6;
    for (int e = wave; e < E; e += nwaves) {
        int r = et[e], s = src[e], d = dst[e];
        float inv = 1.0f / (float)cnt[r * N + d];
        atomicAdd(&h1[(size_t)d * 64 + lane], w1[((size_t)r * N + s) * 64 + lane] * inv);
    }
}
__global__ void x_kernel(float* __restrict__ h1, const float* __restrict__ root1,
                         const float* __restrict__ bias1, int NH) {
    int i = blockIdx.x * blockDim.x + threadIdx.x;
    int stride = gridDim.x * blockDim.x;
    for (; i < NH; i += stride) {
        float v = h1[i] + root1[i] + bias1[i & 63];
        h1[i] = v > 0.0f ? v : 0.0f;
    }
}
__global__ void layer2_kernel(const int* __restrict__ src, const int* __restrict__ dst,
                              const int* __restrict__ et, const int* __restrict__ cnt,
                              const float* __restrict__ x, const float* __restrict__ w2,
                              float* __restrict__ out, int E, int N) {
    int lane = threadIdx.x & 63;
    int l = lane & 31;
    int half = lane >> 5;
    int wave = (blockIdx.x * blockDim.x + threadIdx.x) >> 6;
    int nwaves = (gridDim.x * blockDim.x) >> 6;
    for (int e = wave; e < E; e += nwaves) {
        int r = et[e], s = src[e], d = dst[e];
        float inv = 1.0f / (float)cnt[r * N + d];
        float xv = x[(size_t)s * 64 + lane];
        const float* w2r = w2 + ((size_t)r * 64 + half * 32) * 32 + l;
        float acc = 0.0f;
#pragma unroll
        for (int i2 = 0; i2 < 32; ++i2) acc += __shfl(xv, half * 32 + i2, 64) * w2r[(size_t)i2 * 32];
        acc += __shfl_xor(acc, 32, 64);
        if (half == 0) atomicAdd(&out[(size_t)d * 32 + l], acc * inv);
    }
}
__global__ void final_kernel(float* __restrict__ out, const float* __restrict__ x,
                             const float* __restrict__ root2, const float* __restrict__ bias2,
                             int N) {
    int idx = blockIdx.x * blockDim.x + threadIdx.x;
    int stride = gridDim.x * blockDim.x;
    int total = N * 32;
    for (; idx < total; idx += stride) {
        int n = idx >> 5, l = idx & 31;
        float acc = out[idx] + bias2[l];
        const float* xr = x + (size_t)n * 64;
#pragma unroll
        for (int h = 0; h < 64; ++h) acc += xr[h] * root2[h * 32 + l];
        out[idx] = 1.0f / (1.0f + __expf(-acc));
    }
}

extern "C" void kernel_launch(void* const* d_in, const int* in_sizes, int n_in,
                              void* d_out, int out_size, void* d_ws, size_t ws_size,
                              hipStream_t stream) {
    const int*   edge_index = (const int*)d_in[0];   // [2, E]
    const int*   edge_type  = (const int*)d_in[1];   // [E]
    const float* w1         = (const float*)d_in[2]; // [R, N, 64]
    const float* root1      = (const float*)d_in[3]; // [N, 64]
    const float* bias1      = (const float*)d_in[4]; // [64]
    const float* w2         = (const float*)d_in[5]; // [R, 64, 32]
    const float* root2      = (const float*)d_in[6]; // [64, 32]
    const float* bias2      = (const float*)d_in[7]; // [32]
    float* out = (float*)d_out;

    int E = in_sizes[1];
    int H = in_sizes[4];            // 64
    int L = in_sizes[7];            // 32
    int N = in_sizes[3] / H;
    int R = in_sizes[5] / (H * L);  // <= 16

    const int* src = edge_index;
    const int* dst = edge_index + E;

    int nbkt = (N + BKT_SIZE - 1) / BKT_SIZE;   // 391 for N=50000
    int C = (E + NB1 - 1) / NB1;                // edges per phase-1 block

    // ws layout: [gh nbkt*NB1][gb nbkt*NB1][totals nbkt][bucketStart nbkt]
    //            [payB E][esort E][invtT N*16 f32][start N][deg N][x N*64][z N*16*32 bf16]
    size_t off_gh    = 0;
    size_t off_gb    = off_gh + (size_t)nbkt * NB1 * 4;
    size_t off_tot   = off_gb + (size_t)nbkt * NB1 * 4;
    size_t off_bs    = off_tot + (size_t)nbkt * 4;
    size_t off_payB  = off_bs + (size_t)nbkt * 4 + 64;
    size_t off_esort = off_payB + (size_t)E * 4;
    size_t off_invt  = off_esort + (size_t)E * 4;
    size_t off_start = off_invt + (size_t)N * 16 * 4;
    size_t off_deg   = off_start + (size_t)N * 4;
    size_t off_x     = off_deg + (size_t)N * 4;
    size_t off_z     = off_x + (size_t)N * H * 4;
    size_t need      = off_z + (size_t)N * 16 * L * 2;

    char* ws = (char*)d_ws;
    if (ws_size >= need && R <= 16 && nbkt <= 512 && N < (1 << 20)) {
        int*   gh    = (int*)(ws + off_gh);
        int*   gb    = (int*)(ws + off_gb);
        int*   tot   = (int*)(ws + off_tot);
        int*   bs    = (int*)(ws + off_bs);
        int*   payB  = (int*)(ws + off_payB);
        int*   esort = (int*)(ws + off_esort);
        float* invtT = (float*)(ws + off_invt);
        int*   start = (int*)(ws + off_start);
        int*   deg   = (int*)(ws + off_deg);
        float* x     = (float*)(ws + off_x);
        __hip_bfloat16* z = (__hip_bfloat16*)(ws + off_z);

        p1_hist      <<<NB1, 256, 0, stream>>>(dst, gh, E, C, nbkt);
        scan_a       <<<nbkt, NB1, 0, stream>>>(gh, gb, tot);
        scan_b       <<<1, 512, 0, stream>>>(tot, bs, nbkt);
        p1_scatter   <<<NB1, 256, 0, stream>>>(src, dst, edge_type, gb, bs, payB, E, C, nbkt);
        p2_sort      <<<nbkt, 256, 0, stream>>>(payB, bs, esort, start, deg, N, E, nbkt);
        layer1_gather<<<(N + 3) / 4, 256, 0, stream>>>(esort, start, deg, invtT, w1, root1, bias1, x, N);
        zgemm_kernel <<<2048, 256, 0, stream>>>(x, w2, z, N);
        layer2_gather<<<(N + 3) / 4, 256, 0, stream>>>(esort, start, deg, invtT, z, x, root2, bias2, out, N);
    } else {
        // fallback: round-2 verified atomic path (needs ~16 MB)
        size_t cnt_bytes = (size_t)R * N * sizeof(int);
        int*   cnt = (int*)ws;
        float* h1  = (float*)(ws + cnt_bytes);
        hipMemsetAsync(cnt, 0, cnt_bytes + (size_t)N * H * sizeof(float), stream);
        hipMemsetAsync(out, 0, (size_t)N * L * sizeof(float), stream);
        count_kernel <<<2048, 256, 0, stream>>>(dst, edge_type, cnt, E, N);
        layer1_kernel<<<4096, 256, 0, stream>>>(src, dst, edge_type, cnt, w1, h1, E, N);
        x_kernel     <<<2048, 256, 0, stream>>>(h1, root1, bias1, N * H);
        layer2_kernel<<<4096, 256, 0, stream>>>(src, dst, edge_type, cnt, h1, w2, out, E, N);
        final_kernel <<<2048, 256, 0, stream>>>(out, h1, root2, bias2, N);
    }
}

// Round 8
// 249.024 us; speedup vs baseline: 2.1850x; 1.3057x over previous
//
#include <hip/hip_runtime.h>
#include <hip/hip_bf16.h>

// N=50000 nodes, R<=16 relations, H=64 hidden, L=32 labels, E=1.6M edges
// Zero-global-atomic pipeline:
//   p1_hist -> scan_a -> scan_b -> p1_scatter : dst-bucket partition (LDS atomics)
//   p2_sort: per-bucket 128-bin counting sort + 2048-bin (d,rel) histogram
//            -> esort, start, deg, invtT  (layer1's count sweep eliminated)
//   layer1_gather: wave/dst, float4 lanes (e4*16+h4); 8 edges (2 dwordx4) in flight
//   zgemm: 8 nodes/block-iter, weights in regs (launch_bounds raises VGPR cap),
//          bf162 packed stores
//   layer2_gather: wave/dst; 8 edges in flight; fused root2 matvec + sigmoid

#define BKT_BITS 7
#define BKT_SIZE 128
#define NB1 512

__global__ void p1_hist(const int* __restrict__ dst, int* __restrict__ gh,
                        int E, int C, int nbkt) {
    __shared__ int h[512];
    int t = threadIdx.x;
    for (int i = t; i < nbkt; i += 256) h[i] = 0;
    __syncthreads();
    int b = blockIdx.x;
    int lo = b * C, hi = min(E, lo + C);
    for (int i = lo + t; i < hi; i += 256) atomicAdd(&h[dst[i] >> BKT_BITS], 1);
    __syncthreads();
    for (int i = t; i < nbkt; i += 256) gh[(size_t)i * NB1 + b] = h[i];
}

// block g: Hillis-Steele scan over gh[g][0..NB1) -> gb[g][b]=exclusive, totals[g]
__global__ __launch_bounds__(NB1) void scan_a(const int* __restrict__ gh,
                                              int* __restrict__ gb,
                                              int* __restrict__ totals) {
    __shared__ int buf[NB1];
    int g = blockIdx.x;
    int t = threadIdx.x;
    int v = gh[(size_t)g * NB1 + t];
    buf[t] = v;
    __syncthreads();
    for (int off = 1; off < NB1; off <<= 1) {
        int tmp = (t >= off) ? buf[t - off] : 0;
        __syncthreads();
        buf[t] += tmp;
        __syncthreads();
    }
    gb[(size_t)g * NB1 + t] = buf[t] - v;     // exclusive prefix
    if (t == NB1 - 1) totals[g] = buf[t];
}

// single block: exclusive scan of totals[0..nbkt) -> bucketStart
__global__ __launch_bounds__(512) void scan_b(const int* __restrict__ totals,
                                              int* __restrict__ bucketStart, int nbkt) {
    __shared__ int buf[512];
    int t = threadIdx.x;
    int v = (t < nbkt) ? totals[t] : 0;
    buf[t] = v;
    __syncthreads();
    for (int off = 1; off < 512; off <<= 1) {
        int tmp = (t >= off) ? buf[t - off] : 0;
        __syncthreads();
        buf[t] += tmp;
        __syncthreads();
    }
    if (t < nbkt) bucketStart[t] = buf[t] - v;
}

__global__ void p1_scatter(const int* __restrict__ src, const int* __restrict__ dst,
                           const int* __restrict__ et, const int* __restrict__ gb,
                           const int* __restrict__ bucketStart,
                           int* __restrict__ payB, int E, int C, int nbkt) {
    __shared__ int cur[512];
    int t = threadIdx.x;
    int b = blockIdx.x;
    for (int i = t; i < nbkt; i += 256) cur[i] = bucketStart[i] + gb[(size_t)i * NB1 + b];
    __syncthreads();
    int lo = b * C, hi = min(E, lo + C);
    for (int i = lo + t; i < hi; i += 256) {
        int d = dst[i];
        int p = atomicAdd(&cur[d >> BKT_BITS], 1);   // LDS atomic only
        payB[p] = ((d & (BKT_SIZE - 1)) << 24) | (et[i] << 20) | src[i];
    }
}

// one wg per bucket: 2048-bin (d,rel) histogram -> invtT + deg + start; then
// 128-bin counting-sort scatter. LDS atomics only.
__global__ __launch_bounds__(256) void p2_sort(
        const int* __restrict__ payB, const int* __restrict__ bucketStart,
        int* __restrict__ esort, int* __restrict__ start, int* __restrict__ deg,
        float* __restrict__ invtT, int N, int E, int nbkt) {
    int g = blockIdx.x;
    int lo = bucketStart[g];
    int hi = (g + 1 < nbkt) ? bucketStart[g + 1] : E;
    int n = hi - lo;
    __shared__ int hist2[BKT_SIZE * 16];
    __shared__ int base[BKT_SIZE], cur[BKT_SIZE], degS[BKT_SIZE];
    int t = threadIdx.x;
    for (int i = t; i < BKT_SIZE * 16; i += 256) hist2[i] = 0;
    __syncthreads();
    for (int i = t; i < n; i += 256) {
        int v = payB[lo + i];
        atomicAdd(&hist2[((v >> 24) & (BKT_SIZE - 1)) * 16 + ((v >> 20) & 15)], 1);
    }
    __syncthreads();
    if (t < BKT_SIZE) {
        int d = g * BKT_SIZE + t;
        int tot = 0;
#pragma unroll
        for (int r = 0; r < 16; ++r) {
            int c = hist2[t * 16 + r];
            tot += c;
            if (d < N) invtT[(size_t)d * 16 + r] = (c > 0) ? 1.0f / (float)c : 0.0f;
        }
        base[t] = tot;
        degS[t] = tot;
    }
    __syncthreads();
    if (t == 0) {
        int run = 0;
        for (int i = 0; i < BKT_SIZE; ++i) { int v = base[i]; base[i] = run; run += v; }
    }
    __syncthreads();
    if (t < BKT_SIZE) {
        cur[t] = base[t];
        int d = g * BKT_SIZE + t;
        if (d < N) { start[d] = lo + base[t]; deg[d] = degS[t]; }
    }
    __syncthreads();
    for (int i = t; i < n; i += 256) {
        int v = payB[lo + i];
        int p = atomicAdd(&cur[(v >> 24) & (BKT_SIZE - 1)], 1);   // LDS atomic only
        esort[lo + p] = v & 0x00FFFFFF;    // (et<<20)|src
    }
}

// Wave per dst. lane = e4*16 + h4 (e4 = edge slot, h4 = h-quad). Per 8 edges:
// 2 dwordx4 loads + 4 shfls. Lanes >= lim hold clamped (valid) codes; masked by
// multiply. All shuffles converged.
__global__ __launch_bounds__(256) void layer1_gather(
        const int* __restrict__ esort, const int* __restrict__ start,
        const int* __restrict__ deg, const float* __restrict__ invtT,
        const float* __restrict__ w1, const float* __restrict__ root1,
        const float* __restrict__ bias1, float* __restrict__ x, int N) {
    int lane = threadIdx.x & 63;
    int e4 = lane >> 4;       // 0..3
    int h4 = lane & 15;       // h = h4*4 .. h4*4+3
    int wave = (blockIdx.x * blockDim.x + threadIdx.x) >> 6;
    int nwaves = (gridDim.x * blockDim.x) >> 6;
    for (int d = wave; d < N; d += nwaves) {
        int beg = start[d];
        int dg = deg[d];
        float invc16 = invtT[(size_t)d * 16 + h4];   // lane r=h4 holds 1/cnt[r,d]
        float4 accA = make_float4(0.f, 0.f, 0.f, 0.f);
        float4 accB = make_float4(0.f, 0.f, 0.f, 0.f);
        for (int i = 0; i < dg; i += 64) {
            int v = esort[beg + min(i + lane, dg - 1)];   // coalesced, clamped
            int lim = min(64, dg - i);                    // wave-uniform
            for (int j = 0; j < lim; j += 8) {
                int ca = __shfl(v, j + e4, 64);           // edges j..j+3
                int cb = __shfl(v, j + 4 + e4, 64);       // edges j+4..j+7
                const float4 wa = *(const float4*)(w1 + ((size_t)(ca >> 20) * N + (ca & 0xFFFFF)) * 64 + h4 * 4);
                const float4 wb = *(const float4*)(w1 + ((size_t)(cb >> 20) * N + (cb & 0xFFFFF)) * 64 + h4 * 4);
                float fa = __shfl(invc16, ca >> 20, 64) * ((j + e4 < lim) ? 1.f : 0.f);
                float fb = __shfl(invc16, cb >> 20, 64) * ((j + 4 + e4 < lim) ? 1.f : 0.f);
                accA.x += wa.x * fa; accA.y += wa.y * fa;
                accA.z += wa.z * fa; accA.w += wa.w * fa;
                accB.x += wb.x * fb; accB.y += wb.y * fb;
                accB.z += wb.z * fb; accB.w += wb.w * fb;
            }
        }
        float4 acc;
        acc.x = accA.x + accB.x; acc.y = accA.y + accB.y;
        acc.z = accA.z + accB.z; acc.w = accA.w + accB.w;
        acc.x += __shfl_xor(acc.x, 16, 64); acc.y += __shfl_xor(acc.y, 16, 64);
        acc.z += __shfl_xor(acc.z, 16, 64); acc.w += __shfl_xor(acc.w, 16, 64);
        acc.x += __shfl_xor(acc.x, 32, 64); acc.y += __shfl_xor(acc.y, 32, 64);
        acc.z += __shfl_xor(acc.z, 32, 64); acc.w += __shfl_xor(acc.w, 32, 64);
        if (e4 == 0) {
            float4 rt = *(const float4*)(root1 + (size_t)d * 64 + h4 * 4);
            float4 bs = *(const float4*)(bias1 + h4 * 4);
            float4 o;
            o.x = acc.x + rt.x + bs.x; o.x = o.x > 0.f ? o.x : 0.f;
            o.y = acc.y + rt.y + bs.y; o.y = o.y > 0.f ? o.y : 0.f;
            o.z = acc.z + rt.z + bs.z; o.z = o.z > 0.f ? o.z : 0.f;
            o.w = acc.w + rt.w + bs.w; o.w = o.w > 0.f ? o.w : 0.f;
            *(float4*)(x + (size_t)d * 64 + h4 * 4) = o;
        }
    }
}

// z[n, r*32+l] = sum_h x[n,h] * w2[r,h,l], bf16 pairs. Thread t owns cols
// 2t,2t+1; 8 nodes per iter; weights in registers (launch_bounds -> no spill);
// xs reads are same-address broadcasts (conflict-free).
__global__ __launch_bounds__(256, 2) void zgemm_kernel(
        const float* __restrict__ x, const float* __restrict__ w2,
        __hip_bfloat16* __restrict__ z, int N) {
    __shared__ float xs[8][64];
    int t = threadIdx.x;
    int c0 = t * 2, c1 = t * 2 + 1;
    float wc0[64], wc1[64];
    {
        const float* wp0 = w2 + (size_t)(c0 >> 5) * 2048 + (c0 & 31);
        const float* wp1 = w2 + (size_t)(c1 >> 5) * 2048 + (c1 & 31);
#pragma unroll
        for (int h = 0; h < 64; ++h) { wc0[h] = wp0[h * 32]; wc1[h] = wp1[h * 32]; }
    }
    __hip_bfloat162* z2 = reinterpret_cast<__hip_bfloat162*>(z);
    for (int base = blockIdx.x * 8; base < N; base += gridDim.x * 8) {
        __syncthreads();
        int nn = min(8, N - base);
        for (int k = t; k < nn * 64; k += 256) ((float*)xs)[k] = x[(size_t)base * 64 + k];
        __syncthreads();
#pragma unroll
        for (int n = 0; n < 8; ++n) {
            if (n < nn) {
                float a0 = 0.f, a1 = 0.f;
#pragma unroll
                for (int h = 0; h < 64; ++h) {
                    float xv = xs[n][h];
                    a0 += xv * wc0[h];
                    a1 += xv * wc1[h];
                }
                __hip_bfloat162 p;
                p.x = __float2bfloat16(a0);
                p.y = __float2bfloat16(a1);
                z2[(size_t)(base + n) * 256 + t] = p;
            }
        }
    }
}

// Wave per dst; lane = sub*32 + l. 8 edges in flight per group.
__global__ __launch_bounds__(256) void layer2_gather(
        const int* __restrict__ esort, const int* __restrict__ start,
        const int* __restrict__ deg, const float* __restrict__ invtT,
        const __hip_bfloat16* __restrict__ z, const float* __restrict__ x,
        const float* __restrict__ root2, const float* __restrict__ bias2,
        float* __restrict__ out, int N) {
    int lane = threadIdx.x & 63;
    int sub = lane >> 5;
    int l = lane & 31;
    int wave = (blockIdx.x * blockDim.x + threadIdx.x) >> 6;
    int nwaves = (gridDim.x * blockDim.x) >> 6;
    for (int d = wave; d < N; d += nwaves) {
        int beg = start[d];
        int dg = deg[d];
        float invc = invtT[(size_t)d * 16 + (lane & 15)];
        float xr = x[(size_t)d * 64 + lane];
        float acc0 = 0.f, acc1 = 0.f, acc2 = 0.f, acc3 = 0.f;
        for (int i = 0; i < dg; i += 64) {
            int v = esort[beg + min(i + lane, dg - 1)];
            int lim = min(64, dg - i);                    // wave-uniform
            for (int j = 0; j < lim; j += 8) {
                int c0 = __shfl(v, min(j + 0 + sub, lim - 1), 64);
                int c1 = __shfl(v, min(j + 2 + sub, lim - 1), 64);
                int c2 = __shfl(v, min(j + 4 + sub, lim - 1), 64);
                int c3 = __shfl(v, min(j + 6 + sub, lim - 1), 64);
                float z0 = __bfloat162float(z[((size_t)(c0 & 0xFFFFF) * 16 + (c0 >> 20)) * 32 + l]);
                float z1 = __bfloat162float(z[((size_t)(c1 & 0xFFFFF) * 16 + (c1 >> 20)) * 32 + l]);
                float z2v = __bfloat162float(z[((size_t)(c2 & 0xFFFFF) * 16 + (c2 >> 20)) * 32 + l]);
                float z3 = __bfloat162float(z[((size_t)(c3 & 0xFFFFF) * 16 + (c3 >> 20)) * 32 + l]);
                float f0 = __shfl(invc, c0 >> 20, 64) * ((j + 0 + sub < lim) ? 1.f : 0.f);
                float f1 = __shfl(invc, c1 >> 20, 64) * ((j + 2 + sub < lim) ? 1.f : 0.f);
                float f2 = __shfl(invc, c2 >> 20, 64) * ((j + 4 + sub < lim) ? 1.f : 0.f);
                float f3 = __shfl(invc, c3 >> 20, 64) * ((j + 6 + sub < lim) ? 1.f : 0.f);
                acc0 += z0 * f0;
                acc1 += z1 * f1;
                acc2 += z2v * f2;
                acc3 += z3 * f3;
            }
        }
        float acc = (acc0 + acc1) + (acc2 + acc3);
        float rt = 0.f;
#pragma unroll
        for (int h2 = 0; h2 < 32; ++h2) {
            int h = sub * 32 + h2;
            rt += __shfl(xr, h, 64) * root2[h * 32 + l];
        }
        float tot = acc + rt;
        tot += __shfl_xor(tot, 32, 64);               // combine sub halves
        float logit = tot + bias2[l];
        if (sub == 0) out[(size_t)d * 32 + l] = 1.0f / (1.0f + __expf(-logit));
    }
}

// ---------------- fallback path (small workspace): round-2 verified atomics ----
__global__ void count_kernel(const int* __restrict__ dst, const int* __restrict__ et,
                             int* __restrict__ cnt, int E, int N) {
    int i = blockIdx.x * blockDim.x + threadIdx.x;
    int stride = gridDim.x * blockDim.x;
    for (; i < E; i += stride) atomicAdd(&cnt[et[i] * N + dst[i]], 1);
}
__global__ void layer1_kernel(const int* __restrict__ src, const int* __restrict__ dst,
                              const int* __restrict__ et, const int* __restrict__ cnt,
                              const float* __restrict__ w1, float* __restrict__ h1,
                              int E, int N) {
    int lane = threadIdx.x & 63;
    int wave = (blockIdx.x * blockDim.x + threadIdx.x) >> 6;
    int nwaves = (gridDim.x * blockDim.x) >> 6;
    for (int e = wave; e < E; e += nwaves) {
        int r = et[e], s = src[e], d = dst[e];
        float inv = 1.0f / (float)cnt[r * N + d];
        atomicAdd(&h1[(size_t)d * 64 + lane], w1[((size_t)r * N + s) * 64 + lane] * inv);
    }
}
__global__ void x_kernel(float* __restrict__ h1, const float* __restrict__ root1,
                         const float* __restrict__ bias1, int NH) {
    int i = blockIdx.x * blockDim.x + threadIdx.x;
    int stride = gridDim.x * blockDim.x;
    for (; i < NH; i += stride) {
        float v = h1[i] + root1[i] + bias1[i & 63];
        h1[i] = v > 0.0f ? v : 0.0f;
    }
}
__global__ void layer2_kernel(const int* __restrict__ src, const int* __restrict__ dst,
                              const int* __restrict__ et, const int* __restrict__ cnt,
                              const float* __restrict__ x, const float* __restrict__ w2,
                              float* __restrict__ out, int E, int N) {
    int lane = threadIdx.x & 63;
    int l = lane & 31;
    int half = lane >> 5;
    int wave = (blockIdx.x * blockDim.x + threadIdx.x) >> 6;
    int nwaves = (gridDim.x * blockDim.x) >> 6;
    for (int e = wave; e < E; e += nwaves) {
        int r = et[e], s = src[e], d = dst[e];
        float inv = 1.0f / (float)cnt[r * N + d];
        float xv = x[(size_t)s * 64 + lane];
        const float* w2r = w2 + ((size_t)r * 64 + half * 32) * 32 + l;
        float acc = 0.0f;
#pragma unroll
        for (int i2 = 0; i2 < 32; ++i2) acc += __shfl(xv, half * 32 + i2, 64) * w2r[(size_t)i2 * 32];
        acc += __shfl_xor(acc, 32, 64);
        if (half == 0) atomicAdd(&out[(size_t)d * 32 + l], acc * inv);
    }
}
__global__ void final_kernel(float* __restrict__ out, const float* __restrict__ x,
                             const float* __restrict__ root2, const float* __restrict__ bias2,
                             int N) {
    int idx = blockIdx.x * blockDim.x + threadIdx.x;
    int stride = gridDim.x * blockDim.x;
    int total = N * 32;
    for (; idx < total; idx += stride) {
        int n = idx >> 5, l = idx & 31;
        float acc = out[idx] + bias2[l];
        const float* xr = x + (size_t)n * 64;
#pragma unroll
        for (int h = 0; h < 64; ++h) acc += xr[h] * root2[h * 32 + l];
        out[idx] = 1.0f / (1.0f + __expf(-acc));
    }
}

extern "C" void kernel_launch(void* const* d_in, const int* in_sizes, int n_in,
                              void* d_out, int out_size, void* d_ws, size_t ws_size,
                              hipStream_t stream) {
    const int*   edge_index = (const int*)d_in[0];   // [2, E]
    const int*   edge_type  = (const int*)d_in[1];   // [E]
    const float* w1         = (const float*)d_in[2]; // [R, N, 64]
    const float* root1      = (const float*)d_in[3]; // [N, 64]
    const float* bias1      = (const float*)d_in[4]; // [64]
    const float* w2         = (const float*)d_in[5]; // [R, 64, 32]
    const float* root2      = (const float*)d_in[6]; // [64, 32]
    const float* bias2      = (const float*)d_in[7]; // [32]
    float* out = (float*)d_out;

    int E = in_sizes[1];
    int H = in_sizes[4];            // 64
    int L = in_sizes[7];            // 32
    int N = in_sizes[3] / H;
    int R = in_sizes[5] / (H * L);  // <= 16

    const int* src = edge_index;
    const int* dst = edge_index + E;

    int nbkt = (N + BKT_SIZE - 1) / BKT_SIZE;   // 391 for N=50000
    int C = (E + NB1 - 1) / NB1;                // edges per phase-1 block

    // ws layout: [gh nbkt*NB1][gb nbkt*NB1][totals nbkt][bucketStart nbkt]
    //            [payB E][esort E][invtT N*16 f32][start N][deg N][x N*64][z N*16*32 bf16]
    size_t off_gh    = 0;
    size_t off_gb    = off_gh + (size_t)nbkt * NB1 * 4;
    size_t off_tot   = off_gb + (size_t)nbkt * NB1 * 4;
    size_t off_bs    = off_tot + (size_t)nbkt * 4;
    size_t off_payB  = off_bs + (size_t)nbkt * 4 + 64;
    size_t off_esort = off_payB + (size_t)E * 4;
    size_t off_invt  = off_esort + (size_t)E * 4;
    size_t off_start = off_invt + (size_t)N * 16 * 4;
    size_t off_deg   = off_start + (size_t)N * 4;
    size_t off_x     = off_deg + (size_t)N * 4;
    size_t off_z     = off_x + (size_t)N * H * 4;
    size_t need      = off_z + (size_t)N * 16 * L * 2;

    char* ws = (char*)d_ws;
    if (ws_size >= need && R <= 16 && nbkt <= 512 && N < (1 << 20)) {
        int*   gh    = (int*)(ws + off_gh);
        int*   gb    = (int*)(ws + off_gb);
        int*   tot   = (int*)(ws + off_tot);
        int*   bs    = (int*)(ws + off_bs);
        int*   payB  = (int*)(ws + off_payB);
        int*   esort = (int*)(ws + off_esort);
        float* invtT = (float*)(ws + off_invt);
        int*   start = (int*)(ws + off_start);
        int*   deg   = (int*)(ws + off_deg);
        float* x     = (float*)(ws + off_x);
        __hip_bfloat16* z = (__hip_bfloat16*)(ws + off_z);

        p1_hist      <<<NB1, 256, 0, stream>>>(dst, gh, E, C, nbkt);
        scan_a       <<<nbkt, NB1, 0, stream>>>(gh, gb, tot);
        scan_b       <<<1, 512, 0, stream>>>(tot, bs, nbkt);
        p1_scatter   <<<NB1, 256, 0, stream>>>(src, dst, edge_type, gb, bs, payB, E, C, nbkt);
        p2_sort      <<<nbkt, 256, 0, stream>>>(payB, bs, esort, start, deg, invtT, N, E, nbkt);
        layer1_gather<<<(N + 3) / 4, 256, 0, stream>>>(esort, start, deg, invtT, w1, root1, bias1, x, N);
        zgemm_kernel <<<2048, 256, 0, stream>>>(x, w2, z, N);
        layer2_gather<<<(N + 3) / 4, 256, 0, stream>>>(esort, start, deg, invtT, z, x, root2, bias2, out, N);
    } else {
        // fallback: round-2 verified atomic path (needs ~16 MB)
        size_t cnt_bytes = (size_t)R * N * sizeof(int);
        int*   cnt = (int*)ws;
        float* h1  = (float*)(ws + cnt_bytes);
        hipMemsetAsync(cnt, 0, cnt_bytes + (size_t)N * H * sizeof(float), stream);
        hipMemsetAsync(out, 0, (size_t)N * L * sizeof(float), stream);
        count_kernel <<<2048, 256, 0, stream>>>(dst, edge_type, cnt, E, N);
        layer1_kernel<<<4096, 256, 0, stream>>>(src, dst, edge_type, cnt, w1, h1, E, N);
        x_kernel     <<<2048, 256, 0, stream>>>(h1, root1, bias1, N * H);
        layer2_kernel<<<4096, 256, 0, stream>>>(src, dst, edge_type, cnt, h1, w2, out, E, N);
        final_kernel <<<2048, 256, 0, stream>>>(out, h1, root2, bias2, N);
    }
}

// Round 9
// 239.801 us; speedup vs baseline: 2.2691x; 1.0385x over previous
//
#include <hip/hip_runtime.h>
#include <hip/hip_bf16.h>

// N=50000 nodes, R<=16 relations, H=64 hidden, L=32 labels, E=1.6M edges
// Zero-global-atomic pipeline:
//   p1_hist -> scan_a -> scan_b -> p1_scatter : dst-bucket partition (LDS atomics)
//   p2_sort: per-bucket 128-bin counting sort + 2048-bin (d,rel) histogram
//            -> esort, start, deg, invtT
//   layer1_gather: wave/dst, float4 lanes (e4*16+h4); 16 edges (4 dwordx4) in flight
//   zgemm: 8 nodes/block-iter, weights in regs, bf162 packed stores
//   layer2_gather: wave/dst, bf162 lanes (q*16+m, l-pair per lane); 16 edges in
//                  flight; fused root2 matvec (float2) + bias + sigmoid

#define BKT_BITS 7
#define BKT_SIZE 128
#define NB1 512

__global__ void p1_hist(const int* __restrict__ dst, int* __restrict__ gh,
                        int E, int C, int nbkt) {
    __shared__ int h[512];
    int t = threadIdx.x;
    for (int i = t; i < nbkt; i += 256) h[i] = 0;
    __syncthreads();
    int b = blockIdx.x;
    int lo = b * C, hi = min(E, lo + C);
    for (int i = lo + t; i < hi; i += 256) atomicAdd(&h[dst[i] >> BKT_BITS], 1);
    __syncthreads();
    for (int i = t; i < nbkt; i += 256) gh[(size_t)i * NB1 + b] = h[i];
}

// block g: Hillis-Steele scan over gh[g][0..NB1) -> gb[g][b]=exclusive, totals[g]
__global__ __launch_bounds__(NB1) void scan_a(const int* __restrict__ gh,
                                              int* __restrict__ gb,
                                              int* __restrict__ totals) {
    __shared__ int buf[NB1];
    int g = blockIdx.x;
    int t = threadIdx.x;
    int v = gh[(size_t)g * NB1 + t];
    buf[t] = v;
    __syncthreads();
    for (int off = 1; off < NB1; off <<= 1) {
        int tmp = (t >= off) ? buf[t - off] : 0;
        __syncthreads();
        buf[t] += tmp;
        __syncthreads();
    }
    gb[(size_t)g * NB1 + t] = buf[t] - v;     // exclusive prefix
    if (t == NB1 - 1) totals[g] = buf[t];
}

// single block: exclusive scan of totals[0..nbkt) -> bucketStart
__global__ __launch_bounds__(512) void scan_b(const int* __restrict__ totals,
                                              int* __restrict__ bucketStart, int nbkt) {
    __shared__ int buf[512];
    int t = threadIdx.x;
    int v = (t < nbkt) ? totals[t] : 0;
    buf[t] = v;
    __syncthreads();
    for (int off = 1; off < 512; off <<= 1) {
        int tmp = (t >= off) ? buf[t - off] : 0;
        __syncthreads();
        buf[t] += tmp;
        __syncthreads();
    }
    if (t < nbkt) bucketStart[t] = buf[t] - v;
}

__global__ void p1_scatter(const int* __restrict__ src, const int* __restrict__ dst,
                           const int* __restrict__ et, const int* __restrict__ gb,
                           const int* __restrict__ bucketStart,
                           int* __restrict__ payB, int E, int C, int nbkt) {
    __shared__ int cur[512];
    int t = threadIdx.x;
    int b = blockIdx.x;
    for (int i = t; i < nbkt; i += 256) cur[i] = bucketStart[i] + gb[(size_t)i * NB1 + b];
    __syncthreads();
    int lo = b * C, hi = min(E, lo + C);
    for (int i = lo + t; i < hi; i += 256) {
        int d = dst[i];
        int p = atomicAdd(&cur[d >> BKT_BITS], 1);   // LDS atomic only
        payB[p] = ((d & (BKT_SIZE - 1)) << 24) | (et[i] << 20) | src[i];
    }
}

// one wg per bucket: 2048-bin (d,rel) histogram -> invtT + deg + start; then
// 128-bin counting-sort scatter. LDS atomics only.
__global__ __launch_bounds__(256) void p2_sort(
        const int* __restrict__ payB, const int* __restrict__ bucketStart,
        int* __restrict__ esort, int* __restrict__ start, int* __restrict__ deg,
        float* __restrict__ invtT, int N, int E, int nbkt) {
    int g = blockIdx.x;
    int lo = bucketStart[g];
    int hi = (g + 1 < nbkt) ? bucketStart[g + 1] : E;
    int n = hi - lo;
    __shared__ int hist2[BKT_SIZE * 16];
    __shared__ int base[BKT_SIZE], cur[BKT_SIZE], degS[BKT_SIZE];
    int t = threadIdx.x;
    for (int i = t; i < BKT_SIZE * 16; i += 256) hist2[i] = 0;
    __syncthreads();
    for (int i = t; i < n; i += 256) {
        int v = payB[lo + i];
        atomicAdd(&hist2[((v >> 24) & (BKT_SIZE - 1)) * 16 + ((v >> 20) & 15)], 1);
    }
    __syncthreads();
    if (t < BKT_SIZE) {
        int d = g * BKT_SIZE + t;
        int tot = 0;
#pragma unroll
        for (int r = 0; r < 16; ++r) {
            int c = hist2[t * 16 + r];
            tot += c;
            if (d < N) invtT[(size_t)d * 16 + r] = (c > 0) ? 1.0f / (float)c : 0.0f;
        }
        base[t] = tot;
        degS[t] = tot;
    }
    __syncthreads();
    if (t == 0) {
        int run = 0;
        for (int i = 0; i < BKT_SIZE; ++i) { int v = base[i]; base[i] = run; run += v; }
    }
    __syncthreads();
    if (t < BKT_SIZE) {
        cur[t] = base[t];
        int d = g * BKT_SIZE + t;
        if (d < N) { start[d] = lo + base[t]; deg[d] = degS[t]; }
    }
    __syncthreads();
    for (int i = t; i < n; i += 256) {
        int v = payB[lo + i];
        int p = atomicAdd(&cur[(v >> 24) & (BKT_SIZE - 1)], 1);   // LDS atomic only
        esort[lo + p] = v & 0x00FFFFFF;    // (et<<20)|src
    }
}

// Wave per dst. lane = e4*16 + h4 (e4 = edge slot, h4 = h-quad). 16 edges per
// group: 4 independent dwordx4 loads in flight. Lanes >= lim hold clamped
// (valid) codes, cancelled by multiplicative masks. All shuffles converged.
__global__ __launch_bounds__(256) void layer1_gather(
        const int* __restrict__ esort, const int* __restrict__ start,
        const int* __restrict__ deg, const float* __restrict__ invtT,
        const float* __restrict__ w1, const float* __restrict__ root1,
        const float* __restrict__ bias1, float* __restrict__ x, int N) {
    int lane = threadIdx.x & 63;
    int e4 = lane >> 4;       // 0..3
    int h4 = lane & 15;       // h = h4*4 .. h4*4+3
    int wave = (blockIdx.x * blockDim.x + threadIdx.x) >> 6;
    int nwaves = (gridDim.x * blockDim.x) >> 6;
    for (int d = wave; d < N; d += nwaves) {
        int beg = start[d];
        int dg = deg[d];
        float invc16 = invtT[(size_t)d * 16 + h4];   // lane r holds 1/cnt[r,d]
        float4 accA = make_float4(0.f, 0.f, 0.f, 0.f);
        float4 accB = make_float4(0.f, 0.f, 0.f, 0.f);
        float4 accC = make_float4(0.f, 0.f, 0.f, 0.f);
        float4 accD = make_float4(0.f, 0.f, 0.f, 0.f);
        for (int i = 0; i < dg; i += 64) {
            int v = esort[beg + min(i + lane, dg - 1)];   // coalesced, clamped
            int lim = min(64, dg - i);                    // wave-uniform
            for (int j = 0; j < lim; j += 16) {
                int cA = __shfl(v, j + e4, 64);
                int cB = __shfl(v, j + 4 + e4, 64);
                int cC = __shfl(v, j + 8 + e4, 64);
                int cD = __shfl(v, j + 12 + e4, 64);
                const float4 wA = *(const float4*)(w1 + ((size_t)(cA >> 20) * N + (cA & 0xFFFFF)) * 64 + h4 * 4);
                const float4 wB = *(const float4*)(w1 + ((size_t)(cB >> 20) * N + (cB & 0xFFFFF)) * 64 + h4 * 4);
                const float4 wC = *(const float4*)(w1 + ((size_t)(cC >> 20) * N + (cC & 0xFFFFF)) * 64 + h4 * 4);
                const float4 wD = *(const float4*)(w1 + ((size_t)(cD >> 20) * N + (cD & 0xFFFFF)) * 64 + h4 * 4);
                float fA = __shfl(invc16, cA >> 20, 64) * ((j + e4 < lim) ? 1.f : 0.f);
                float fB = __shfl(invc16, cB >> 20, 64) * ((j + 4 + e4 < lim) ? 1.f : 0.f);
                float fC = __shfl(invc16, cC >> 20, 64) * ((j + 8 + e4 < lim) ? 1.f : 0.f);
                float fD = __shfl(invc16, cD >> 20, 64) * ((j + 12 + e4 < lim) ? 1.f : 0.f);
                accA.x += wA.x * fA; accA.y += wA.y * fA;
                accA.z += wA.z * fA; accA.w += wA.w * fA;
                accB.x += wB.x * fB; accB.y += wB.y * fB;
                accB.z += wB.z * fB; accB.w += wB.w * fB;
                accC.x += wC.x * fC; accC.y += wC.y * fC;
                accC.z += wC.z * fC; accC.w += wC.w * fC;
                accD.x += wD.x * fD; accD.y += wD.y * fD;
                accD.z += wD.z * fD; accD.w += wD.w * fD;
            }
        }
        float4 acc;
        acc.x = (accA.x + accB.x) + (accC.x + accD.x);
        acc.y = (accA.y + accB.y) + (accC.y + accD.y);
        acc.z = (accA.z + accB.z) + (accC.z + accD.z);
        acc.w = (accA.w + accB.w) + (accC.w + accD.w);
        acc.x += __shfl_xor(acc.x, 16, 64); acc.y += __shfl_xor(acc.y, 16, 64);
        acc.z += __shfl_xor(acc.z, 16, 64); acc.w += __shfl_xor(acc.w, 16, 64);
        acc.x += __shfl_xor(acc.x, 32, 64); acc.y += __shfl_xor(acc.y, 32, 64);
        acc.z += __shfl_xor(acc.z, 32, 64); acc.w += __shfl_xor(acc.w, 32, 64);
        if (e4 == 0) {
            float4 rt = *(const float4*)(root1 + (size_t)d * 64 + h4 * 4);
            float4 bs = *(const float4*)(bias1 + h4 * 4);
            float4 o;
            o.x = acc.x + rt.x + bs.x; o.x = o.x > 0.f ? o.x : 0.f;
            o.y = acc.y + rt.y + bs.y; o.y = o.y > 0.f ? o.y : 0.f;
            o.z = acc.z + rt.z + bs.z; o.z = o.z > 0.f ? o.z : 0.f;
            o.w = acc.w + rt.w + bs.w; o.w = o.w > 0.f ? o.w : 0.f;
            *(float4*)(x + (size_t)d * 64 + h4 * 4) = o;
        }
    }
}

// z[n, r*32+l] = sum_h x[n,h] * w2[r,h,l], bf16 pairs. Thread t owns cols
// 2t,2t+1; 8 nodes per iter; weights in registers; xs reads are broadcasts.
__global__ __launch_bounds__(256, 2) void zgemm_kernel(
        const float* __restrict__ x, const float* __restrict__ w2,
        __hip_bfloat16* __restrict__ z, int N) {
    __shared__ float xs[8][64];
    int t = threadIdx.x;
    int c0 = t * 2, c1 = t * 2 + 1;
    float wc0[64], wc1[64];
    {
        const float* wp0 = w2 + (size_t)(c0 >> 5) * 2048 + (c0 & 31);
        const float* wp1 = w2 + (size_t)(c1 >> 5) * 2048 + (c1 & 31);
#pragma unroll
        for (int h = 0; h < 64; ++h) { wc0[h] = wp0[h * 32]; wc1[h] = wp1[h * 32]; }
    }
    __hip_bfloat162* z2 = reinterpret_cast<__hip_bfloat162*>(z);
    for (int base = blockIdx.x * 8; base < N; base += gridDim.x * 8) {
        __syncthreads();
        int nn = min(8, N - base);
        for (int k = t; k < nn * 64; k += 256) ((float*)xs)[k] = x[(size_t)base * 64 + k];
        __syncthreads();
#pragma unroll
        for (int n = 0; n < 8; ++n) {
            if (n < nn) {
                float a0 = 0.f, a1 = 0.f;
#pragma unroll
                for (int h = 0; h < 64; ++h) {
                    float xv = xs[n][h];
                    a0 += xv * wc0[h];
                    a1 += xv * wc1[h];
                }
                __hip_bfloat162 p;
                p.x = __float2bfloat16(a0);
                p.y = __float2bfloat16(a1);
                z2[(size_t)(base + n) * 256 + t] = p;
            }
        }
    }
}

// Wave per dst. lane = q*16 + m: q = edge slot (0..3), m = l-pair (l=2m,2m+1).
// 16 edges per group via 4 bf162 loads in flight; fused root2 (float2) matvec
// + bias + sigmoid; float2 stores. All shuffles converged.
__global__ __launch_bounds__(256) void layer2_gather(
        const int* __restrict__ esort, const int* __restrict__ start,
        const int* __restrict__ deg, const float* __restrict__ invtT,
        const __hip_bfloat16* __restrict__ z, const float* __restrict__ x,
        const float* __restrict__ root2, const float* __restrict__ bias2,
        float* __restrict__ out, int N) {
    int lane = threadIdx.x & 63;
    int q = lane >> 4;        // 0..3
    int m = lane & 15;        // l = 2m, 2m+1
    int wave = (blockIdx.x * blockDim.x + threadIdx.x) >> 6;
    int nwaves = (gridDim.x * blockDim.x) >> 6;
    const __hip_bfloat162* z2 = reinterpret_cast<const __hip_bfloat162*>(z);
    for (int d = wave; d < N; d += nwaves) {
        int beg = start[d];
        int dg = deg[d];
        float invc = invtT[(size_t)d * 16 + m];     // lane r (<16) holds 1/cnt[r,d]
        float xr = x[(size_t)d * 64 + lane];
        float axA = 0.f, ayA = 0.f, axB = 0.f, ayB = 0.f;
        float axC = 0.f, ayC = 0.f, axD = 0.f, ayD = 0.f;
        for (int i = 0; i < dg; i += 64) {
            int v = esort[beg + min(i + lane, dg - 1)];
            int lim = min(64, dg - i);                    // wave-uniform
            for (int j = 0; j < lim; j += 16) {
                int cA = __shfl(v, j + q, 64);
                int cB = __shfl(v, j + 4 + q, 64);
                int cC = __shfl(v, j + 8 + q, 64);
                int cD = __shfl(v, j + 12 + q, 64);
                __hip_bfloat162 zA = z2[((size_t)(cA & 0xFFFFF) * 16 + (cA >> 20)) * 16 + m];
                __hip_bfloat162 zB = z2[((size_t)(cB & 0xFFFFF) * 16 + (cB >> 20)) * 16 + m];
                __hip_bfloat162 zC = z2[((size_t)(cC & 0xFFFFF) * 16 + (cC >> 20)) * 16 + m];
                __hip_bfloat162 zD = z2[((size_t)(cD & 0xFFFFF) * 16 + (cD >> 20)) * 16 + m];
                float fA = __shfl(invc, cA >> 20, 64) * ((j + q < lim) ? 1.f : 0.f);
                float fB = __shfl(invc, cB >> 20, 64) * ((j + 4 + q < lim) ? 1.f : 0.f);
                float fC = __shfl(invc, cC >> 20, 64) * ((j + 8 + q < lim) ? 1.f : 0.f);
                float fD = __shfl(invc, cD >> 20, 64) * ((j + 12 + q < lim) ? 1.f : 0.f);
                axA += __bfloat162float(zA.x) * fA; ayA += __bfloat162float(zA.y) * fA;
                axB += __bfloat162float(zB.x) * fB; ayB += __bfloat162float(zB.y) * fB;
                axC += __bfloat162float(zC.x) * fC; ayC += __bfloat162float(zC.y) * fC;
                axD += __bfloat162float(zD.x) * fD; ayD += __bfloat162float(zD.y) * fD;
            }
        }
        float tx = (axA + axB) + (axC + axD);
        float ty = (ayA + ayB) + (ayC + ayD);
        // root2 matvec: this lane covers h = q*16 + h2, cols 2m and 2m+1
#pragma unroll
        for (int h2 = 0; h2 < 16; ++h2) {
            int h = q * 16 + h2;
            float xs = __shfl(xr, h, 64);
            float2 rw = *(const float2*)(root2 + h * 32 + 2 * m);
            tx += xs * rw.x;
            ty += xs * rw.y;
        }
        tx += __shfl_xor(tx, 16, 64); ty += __shfl_xor(ty, 16, 64);
        tx += __shfl_xor(tx, 32, 64); ty += __shfl_xor(ty, 32, 64);
        if (q == 0) {
            float2 o;
            o.x = 1.0f / (1.0f + __expf(-(tx + bias2[2 * m])));
            o.y = 1.0f / (1.0f + __expf(-(ty + bias2[2 * m + 1])));
            *(float2*)(out + (size_t)d * 32 + 2 * m) = o;
        }
    }
}

// ---------------- fallback path (small workspace): round-2 verified atomics ----
__global__ void count_kernel(const int* __restrict__ dst, const int* __restrict__ et,
                             int* __restrict__ cnt, int E, int N) {
    int i = blockIdx.x * blockDim.x + threadIdx.x;
    int stride = gridDim.x * blockDim.x;
    for (; i < E; i += stride) atomicAdd(&cnt[et[i] * N + dst[i]], 1);
}
__global__ void layer1_kernel(const int* __restrict__ src, const int* __restrict__ dst,
                              const int* __restrict__ et, const int* __restrict__ cnt,
                              const float* __restrict__ w1, float* __restrict__ h1,
                              int E, int N) {
    int lane = threadIdx.x & 63;
    int wave = (blockIdx.x * blockDim.x + threadIdx.x) >> 6;
    int nwaves = (gridDim.x * blockDim.x) >> 6;
    for (int e = wave; e < E; e += nwaves) {
        int r = et[e], s = src[e], d = dst[e];
        float inv = 1.0f / (float)cnt[r * N + d];
        atomicAdd(&h1[(size_t)d * 64 + lane], w1[((size_t)r * N + s) * 64 + lane] * inv);
    }
}
__global__ void x_kernel(float* __restrict__ h1, const float* __restrict__ root1,
                         const float* __restrict__ bias1, int NH) {
    int i = blockIdx.x * blockDim.x + threadIdx.x;
    int stride = gridDim.x * blockDim.x;
    for (; i < NH; i += stride) {
        float v = h1[i] + root1[i] + bias1[i & 63];
        h1[i] = v > 0.0f ? v : 0.0f;
    }
}
__global__ void layer2_kernel(const int* __restrict__ src, const int* __restrict__ dst,
                              const int* __restrict__ et, const int* __restrict__ cnt,
                              const float* __restrict__ x, const float* __restrict__ w2,
                              float* __restrict__ out, int E, int N) {
    int lane = threadIdx.x & 63;
    int l = lane & 31;
    int half = lane >> 5;
    int wave = (blockIdx.x * blockDim.x + threadIdx.x) >> 6;
    int nwaves = (gridDim.x * blockDim.x) >> 6;
    for (int e = wave; e < E; e += nwaves) {
        int r = et[e], s = src[e], d = dst[e];
        float inv = 1.0f / (float)cnt[r * N + d];
        float xv = x[(size_t)s * 64 + lane];
        const float* w2r = w2 + ((size_t)r * 64 + half * 32) * 32 + l;
        float acc = 0.0f;
#pragma unroll
        for (int i2 = 0; i2 < 32; ++i2) acc += __shfl(xv, half * 32 + i2, 64) * w2r[(size_t)i2 * 32];
        acc += __shfl_xor(acc, 32, 64);
        if (half == 0) atomicAdd(&out[(size_t)d * 32 + l], acc * inv);
    }
}
__global__ void final_kernel(float* __restrict__ out, const float* __restrict__ x,
                             const float* __restrict__ root2, const float* __restrict__ bias2,
                             int N) {
    int idx = blockIdx.x * blockDim.x + threadIdx.x;
    int stride = gridDim.x * blockDim.x;
    int total = N * 32;
    for (; idx < total; idx += stride) {
        int n = idx >> 5, l = idx & 31;
        float acc = out[idx] + bias2[l];
        const float* xr = x + (size_t)n * 64;
#pragma unroll
        for (int h = 0; h < 64; ++h) acc += xr[h] * root2[h * 32 + l];
        out[idx] = 1.0f / (1.0f + __expf(-acc));
    }
}

extern "C" void kernel_launch(void* const* d_in, const int* in_sizes, int n_in,
                              void* d_out, int out_size, void* d_ws, size_t ws_size,
                              hipStream_t stream) {
    const int*   edge_index = (const int*)d_in[0];   // [2, E]
    const int*   edge_type  = (const int*)d_in[1];   // [E]
    const float* w1         = (const float*)d_in[2]; // [R, N, 64]
    const float* root1      = (const float*)d_in[3]; // [N, 64]
    const float* bias1      = (const float*)d_in[4]; // [64]
    const float* w2         = (const float*)d_in[5]; // [R, 64, 32]
    const float* root2      = (const float*)d_in[6]; // [64, 32]
    const float* bias2      = (const float*)d_in[7]; // [32]
    float* out = (float*)d_out;

    int E = in_sizes[1];
    int H = in_sizes[4];            // 64
    int L = in_sizes[7];            // 32
    int N = in_sizes[3] / H;
    int R = in_sizes[5] / (H * L);  // <= 16

    const int* src = edge_index;
    const int* dst = edge_index + E;

    int nbkt = (N + BKT_SIZE - 1) / BKT_SIZE;   // 391 for N=50000
    int C = (E + NB1 - 1) / NB1;                // edges per phase-1 block

    // ws layout: [gh nbkt*NB1][gb nbkt*NB1][totals nbkt][bucketStart nbkt]
    //            [payB E][esort E][invtT N*16 f32][start N][deg N][x N*64][z N*16*32 bf16]
    size_t off_gh    = 0;
    size_t off_gb    = off_gh + (size_t)nbkt * NB1 * 4;
    size_t off_tot   = off_gb + (size_t)nbkt * NB1 * 4;
    size_t off_bs    = off_tot + (size_t)nbkt * 4;
    size_t off_payB  = off_bs + (size_t)nbkt * 4 + 64;
    size_t off_esort = off_payB + (size_t)E * 4;
    size_t off_invt  = off_esort + (size_t)E * 4;
    size_t off_start = off_invt + (size_t)N * 16 * 4;
    size_t off_deg   = off_start + (size_t)N * 4;
    size_t off_x     = off_deg + (size_t)N * 4;
    size_t off_z     = off_x + (size_t)N * H * 4;
    size_t need      = off_z + (size_t)N * 16 * L * 2;

    char* ws = (char*)d_ws;
    if (ws_size >= need && R <= 16 && nbkt <= 512 && N < (1 << 20)) {
        int*   gh    = (int*)(ws + off_gh);
        int*   gb    = (int*)(ws + off_gb);
        int*   tot   = (int*)(ws + off_tot);
        int*   bs    = (int*)(ws + off_bs);
        int*   payB  = (int*)(ws + off_payB);
        int*   esort = (int*)(ws + off_esort);
        float* invtT = (float*)(ws + off_invt);
        int*   start = (int*)(ws + off_start);
        int*   deg   = (int*)(ws + off_deg);
        float* x     = (float*)(ws + off_x);
        __hip_bfloat16* z = (__hip_bfloat16*)(ws + off_z);

        p1_hist      <<<NB1, 256, 0, stream>>>(dst, gh, E, C, nbkt);
        scan_a       <<<nbkt, NB1, 0, stream>>>(gh, gb, tot);
        scan_b       <<<1, 512, 0, stream>>>(tot, bs, nbkt);
        p1_scatter   <<<NB1, 256, 0, stream>>>(src, dst, edge_type, gb, bs, payB, E, C, nbkt);
        p2_sort      <<<nbkt, 256, 0, stream>>>(payB, bs, esort, start, deg, invtT, N, E, nbkt);
        layer1_gather<<<(N + 3) / 4, 256, 0, stream>>>(esort, start, deg, invtT, w1, root1, bias1, x, N);
        zgemm_kernel <<<2048, 256, 0, stream>>>(x, w2, z, N);
        layer2_gather<<<(N + 3) / 4, 256, 0, stream>>>(esort, start, deg, invtT, z, x, root2, bias2, out, N);
    } else {
        // fallback: round-2 verified atomic path (needs ~16 MB)
        size_t cnt_bytes = (size_t)R * N * sizeof(int);
        int*   cnt = (int*)ws;
        float* h1  = (float*)(ws + cnt_bytes);
        hipMemsetAsync(cnt, 0, cnt_bytes + (size_t)N * H * sizeof(float), stream);
        hipMemsetAsync(out, 0, (size_t)N * L * sizeof(float), stream);
        count_kernel <<<2048, 256, 0, stream>>>(dst, edge_type, cnt, E, N);
        layer1_kernel<<<4096, 256, 0, stream>>>(src, dst, edge_type, cnt, w1, h1, E, N);
        x_kernel     <<<2048, 256, 0, stream>>>(h1, root1, bias1, N * H);
        layer2_kernel<<<4096, 256, 0, stream>>>(src, dst, edge_type, cnt, h1, w2, out, E, N);
        final_kernel <<<2048, 256, 0, stream>>>(out, h1, root2, bias2, N);
    }
}

// Round 10
// 230.131 us; speedup vs baseline: 2.3644x; 1.0420x over previous
//
#include <hip/hip_runtime.h>
#include <hip/hip_bf16.h>

// N=50000 nodes, R<=16 relations, H=64 hidden, L=32 labels, E=1.6M edges
// Zero-global-atomic pipeline:
//   p1_hist -> scan_a -> scan_b -> p1_scatter : dst-bucket partition (LDS atomics)
//   p2_sort: single-pass LDS-staged counting sort + 2048-bin (d,rel) histogram
//            -> esort, start, deg, invtT
//   layer1_gather: wave/dst, float4 lanes (e4*16+h4); 16 edges (4 dwordx4) in flight
//   zgemm: 8 nodes/block-iter, weights in regs, bf162 packed stores
//   layer2_gather: 2048 blocks, ~6 dsts/wave; root2/bias2 preloaded in regs;
//                  bf162 lanes (q*16+m); 16 edges in flight; fused sigmoid

#define BKT_BITS 7
#define BKT_SIZE 128
#define NB1 512
#define P2CAP 6144

__global__ void p1_hist(const int* __restrict__ dst, int* __restrict__ gh,
                        int E, int C, int nbkt) {
    __shared__ int h[512];
    int t = threadIdx.x;
    for (int i = t; i < nbkt; i += 256) h[i] = 0;
    __syncthreads();
    int b = blockIdx.x;
    int lo = b * C, hi = min(E, lo + C);
    for (int i = lo + t; i < hi; i += 256) atomicAdd(&h[dst[i] >> BKT_BITS], 1);
    __syncthreads();
    for (int i = t; i < nbkt; i += 256) gh[(size_t)i * NB1 + b] = h[i];
}

// block g: Hillis-Steele scan over gh[g][0..NB1) -> gb[g][b]=exclusive, totals[g]
__global__ __launch_bounds__(NB1) void scan_a(const int* __restrict__ gh,
                                              int* __restrict__ gb,
                                              int* __restrict__ totals) {
    __shared__ int buf[NB1];
    int g = blockIdx.x;
    int t = threadIdx.x;
    int v = gh[(size_t)g * NB1 + t];
    buf[t] = v;
    __syncthreads();
    for (int off = 1; off < NB1; off <<= 1) {
        int tmp = (t >= off) ? buf[t - off] : 0;
        __syncthreads();
        buf[t] += tmp;
        __syncthreads();
    }
    gb[(size_t)g * NB1 + t] = buf[t] - v;     // exclusive prefix
    if (t == NB1 - 1) totals[g] = buf[t];
}

// single block: exclusive scan of totals[0..nbkt) -> bucketStart
__global__ __launch_bounds__(512) void scan_b(const int* __restrict__ totals,
                                              int* __restrict__ bucketStart, int nbkt) {
    __shared__ int buf[512];
    int t = threadIdx.x;
    int v = (t < nbkt) ? totals[t] : 0;
    buf[t] = v;
    __syncthreads();
    for (int off = 1; off < 512; off <<= 1) {
        int tmp = (t >= off) ? buf[t - off] : 0;
        __syncthreads();
        buf[t] += tmp;
        __syncthreads();
    }
    if (t < nbkt) bucketStart[t] = buf[t] - v;
}

__global__ void p1_scatter(const int* __restrict__ src, const int* __restrict__ dst,
                           const int* __restrict__ et, const int* __restrict__ gb,
                           const int* __restrict__ bucketStart,
                           int* __restrict__ payB, int E, int C, int nbkt) {
    __shared__ int cur[512];
    int t = threadIdx.x;
    int b = blockIdx.x;
    for (int i = t; i < nbkt; i += 256) cur[i] = bucketStart[i] + gb[(size_t)i * NB1 + b];
    __syncthreads();
    int lo = b * C, hi = min(E, lo + C);
    for (int i = lo + t; i < hi; i += 256) {
        int d = dst[i];
        int p = atomicAdd(&cur[d >> BKT_BITS], 1);   // LDS atomic only
        payB[p] = ((d & (BKT_SIZE - 1)) << 24) | (et[i] << 20) | src[i];
    }
}

// one wg per bucket: single global read of payB (staged to LDS) + 2048-bin
// (d,rel) histogram -> invtT + deg + start; then LDS counting-sort scatter.
__global__ __launch_bounds__(256) void p2_sort(
        const int* __restrict__ payB, const int* __restrict__ bucketStart,
        int* __restrict__ esort, int* __restrict__ start, int* __restrict__ deg,
        float* __restrict__ invtT, int N, int E, int nbkt) {
    int g = blockIdx.x;
    int lo = bucketStart[g];
    int hi = (g + 1 < nbkt) ? bucketStart[g + 1] : E;
    int n = hi - lo;
    __shared__ int codes[P2CAP];
    __shared__ int hist2[BKT_SIZE * 16];
    __shared__ int base[BKT_SIZE], cur[BKT_SIZE], degS[BKT_SIZE];
    int t = threadIdx.x;
    bool fits = (n <= P2CAP);
    for (int i = t; i < BKT_SIZE * 16; i += 256) hist2[i] = 0;
    __syncthreads();
    if (fits) {
        for (int i = t; i < n; i += 256) {
            int v = payB[lo + i];
            codes[i] = v;                            // stage + hist in one pass
            atomicAdd(&hist2[((v >> 24) & (BKT_SIZE - 1)) * 16 + ((v >> 20) & 15)], 1);
        }
    } else {
        for (int i = t; i < n; i += 256) {
            int v = payB[lo + i];
            atomicAdd(&hist2[((v >> 24) & (BKT_SIZE - 1)) * 16 + ((v >> 20) & 15)], 1);
        }
    }
    __syncthreads();
    if (t < BKT_SIZE) {
        int d = g * BKT_SIZE + t;
        int tot = 0;
#pragma unroll
        for (int r = 0; r < 16; ++r) {
            int c = hist2[t * 16 + r];
            tot += c;
            if (d < N) invtT[(size_t)d * 16 + r] = (c > 0) ? 1.0f / (float)c : 0.0f;
        }
        base[t] = tot;
        degS[t] = tot;
    }
    __syncthreads();
    if (t == 0) {
        int run = 0;
        for (int i = 0; i < BKT_SIZE; ++i) { int v = base[i]; base[i] = run; run += v; }
    }
    __syncthreads();
    if (t < BKT_SIZE) {
        cur[t] = base[t];
        int d = g * BKT_SIZE + t;
        if (d < N) { start[d] = lo + base[t]; deg[d] = degS[t]; }
    }
    __syncthreads();
    if (fits) {
        for (int i = t; i < n; i += 256) {
            int v = codes[i];
            int p = atomicAdd(&cur[(v >> 24) & (BKT_SIZE - 1)], 1);   // LDS atomic
            esort[lo + p] = v & 0x00FFFFFF;    // (et<<20)|src
        }
    } else {
        for (int i = t; i < n; i += 256) {
            int v = payB[lo + i];
            int p = atomicAdd(&cur[(v >> 24) & (BKT_SIZE - 1)], 1);
            esort[lo + p] = v & 0x00FFFFFF;
        }
    }
}

// Wave per dst. lane = e4*16 + h4 (e4 = edge slot, h4 = h-quad). 16 edges per
// group: 4 independent dwordx4 loads in flight. Lanes >= lim hold clamped
// (valid) codes, cancelled by multiplicative masks. All shuffles converged.
__global__ __launch_bounds__(256) void layer1_gather(
        const int* __restrict__ esort, const int* __restrict__ start,
        const int* __restrict__ deg, const float* __restrict__ invtT,
        const float* __restrict__ w1, const float* __restrict__ root1,
        const float* __restrict__ bias1, float* __restrict__ x, int N) {
    int lane = threadIdx.x & 63;
    int e4 = lane >> 4;       // 0..3
    int h4 = lane & 15;       // h = h4*4 .. h4*4+3
    int wave = (blockIdx.x * blockDim.x + threadIdx.x) >> 6;
    int nwaves = (gridDim.x * blockDim.x) >> 6;
    for (int d = wave; d < N; d += nwaves) {
        int beg = start[d];
        int dg = deg[d];
        float invc16 = invtT[(size_t)d * 16 + h4];   // lane r holds 1/cnt[r,d]
        float4 accA = make_float4(0.f, 0.f, 0.f, 0.f);
        float4 accB = make_float4(0.f, 0.f, 0.f, 0.f);
        float4 accC = make_float4(0.f, 0.f, 0.f, 0.f);
        float4 accD = make_float4(0.f, 0.f, 0.f, 0.f);
        for (int i = 0; i < dg; i += 64) {
            int v = esort[beg + min(i + lane, dg - 1)];   // coalesced, clamped
            int lim = min(64, dg - i);                    // wave-uniform
            for (int j = 0; j < lim; j += 16) {
                int cA = __shfl(v, j + e4, 64);
                int cB = __shfl(v, j + 4 + e4, 64);
                int cC = __shfl(v, j + 8 + e4, 64);
                int cD = __shfl(v, j + 12 + e4, 64);
                const float4 wA = *(const float4*)(w1 + ((size_t)(cA >> 20) * N + (cA & 0xFFFFF)) * 64 + h4 * 4);
                const float4 wB = *(const float4*)(w1 + ((size_t)(cB >> 20) * N + (cB & 0xFFFFF)) * 64 + h4 * 4);
                const float4 wC = *(const float4*)(w1 + ((size_t)(cC >> 20) * N + (cC & 0xFFFFF)) * 64 + h4 * 4);
                const float4 wD = *(const float4*)(w1 + ((size_t)(cD >> 20) * N + (cD & 0xFFFFF)) * 64 + h4 * 4);
                float fA = __shfl(invc16, cA >> 20, 64) * ((j + e4 < lim) ? 1.f : 0.f);
                float fB = __shfl(invc16, cB >> 20, 64) * ((j + 4 + e4 < lim) ? 1.f : 0.f);
                float fC = __shfl(invc16, cC >> 20, 64) * ((j + 8 + e4 < lim) ? 1.f : 0.f);
                float fD = __shfl(invc16, cD >> 20, 64) * ((j + 12 + e4 < lim) ? 1.f : 0.f);
                accA.x += wA.x * fA; accA.y += wA.y * fA;
                accA.z += wA.z * fA; accA.w += wA.w * fA;
                accB.x += wB.x * fB; accB.y += wB.y * fB;
                accB.z += wB.z * fB; accB.w += wB.w * fB;
                accC.x += wC.x * fC; accC.y += wC.y * fC;
                accC.z += wC.z * fC; accC.w += wC.w * fC;
                accD.x += wD.x * fD; accD.y += wD.y * fD;
                accD.z += wD.z * fD; accD.w += wD.w * fD;
            }
        }
        float4 acc;
        acc.x = (accA.x + accB.x) + (accC.x + accD.x);
        acc.y = (accA.y + accB.y) + (accC.y + accD.y);
        acc.z = (accA.z + accB.z) + (accC.z + accD.z);
        acc.w = (accA.w + accB.w) + (accC.w + accD.w);
        acc.x += __shfl_xor(acc.x, 16, 64); acc.y += __shfl_xor(acc.y, 16, 64);
        acc.z += __shfl_xor(acc.z, 16, 64); acc.w += __shfl_xor(acc.w, 16, 64);
        acc.x += __shfl_xor(acc.x, 32, 64); acc.y += __shfl_xor(acc.y, 32, 64);
        acc.z += __shfl_xor(acc.z, 32, 64); acc.w += __shfl_xor(acc.w, 32, 64);
        if (e4 == 0) {
            float4 rt = *(const float4*)(root1 + (size_t)d * 64 + h4 * 4);
            float4 bs = *(const float4*)(bias1 + h4 * 4);
            float4 o;
            o.x = acc.x + rt.x + bs.x; o.x = o.x > 0.f ? o.x : 0.f;
            o.y = acc.y + rt.y + bs.y; o.y = o.y > 0.f ? o.y : 0.f;
            o.z = acc.z + rt.z + bs.z; o.z = o.z > 0.f ? o.z : 0.f;
            o.w = acc.w + rt.w + bs.w; o.w = o.w > 0.f ? o.w : 0.f;
            *(float4*)(x + (size_t)d * 64 + h4 * 4) = o;
        }
    }
}

// z[n, r*32+l] = sum_h x[n,h] * w2[r,h,l], bf16 pairs. Thread t owns cols
// 2t,2t+1; 8 nodes per iter; weights in registers; xs reads are broadcasts.
__global__ __launch_bounds__(256, 2) void zgemm_kernel(
        const float* __restrict__ x, const float* __restrict__ w2,
        __hip_bfloat16* __restrict__ z, int N) {
    __shared__ float xs[8][64];
    int t = threadIdx.x;
    int c0 = t * 2, c1 = t * 2 + 1;
    float wc0[64], wc1[64];
    {
        const float* wp0 = w2 + (size_t)(c0 >> 5) * 2048 + (c0 & 31);
        const float* wp1 = w2 + (size_t)(c1 >> 5) * 2048 + (c1 & 31);
#pragma unroll
        for (int h = 0; h < 64; ++h) { wc0[h] = wp0[h * 32]; wc1[h] = wp1[h * 32]; }
    }
    __hip_bfloat162* z2 = reinterpret_cast<__hip_bfloat162*>(z);
    for (int base = blockIdx.x * 8; base < N; base += gridDim.x * 8) {
        __syncthreads();
        int nn = min(8, N - base);
        for (int k = t; k < nn * 64; k += 256) ((float*)xs)[k] = x[(size_t)base * 64 + k];
        __syncthreads();
#pragma unroll
        for (int n = 0; n < 8; ++n) {
            if (n < nn) {
                float a0 = 0.f, a1 = 0.f;
#pragma unroll
                for (int h = 0; h < 64; ++h) {
                    float xv = xs[n][h];
                    a0 += xv * wc0[h];
                    a1 += xv * wc1[h];
                }
                __hip_bfloat162 p;
                p.x = __float2bfloat16(a0);
                p.y = __float2bfloat16(a1);
                z2[(size_t)(base + n) * 256 + t] = p;
            }
        }
    }
}

// lane = q*16 + m: q = edge slot (0..3), m = l-pair (l=2m,2m+1). 16 edges per
// group via 4 bf162 loads in flight. root2/bias2 preloaded per-wave (multi-dst
// amortized). All shuffles converged.
__global__ __launch_bounds__(256) void layer2_gather(
        const int* __restrict__ esort, const int* __restrict__ start,
        const int* __restrict__ deg, const float* __restrict__ invtT,
        const __hip_bfloat16* __restrict__ z, const float* __restrict__ x,
        const float* __restrict__ root2, const float* __restrict__ bias2,
        float* __restrict__ out, int N) {
    int lane = threadIdx.x & 63;
    int q = lane >> 4;        // 0..3
    int m = lane & 15;        // l = 2m, 2m+1
    int wave = (blockIdx.x * blockDim.x + threadIdx.x) >> 6;
    int nwaves = (gridDim.x * blockDim.x) >> 6;
    const __hip_bfloat162* z2 = reinterpret_cast<const __hip_bfloat162*>(z);
    // per-wave invariants: root2 rows h = q*16+h2, cols 2m,2m+1; bias pair
    float2 rw[16];
#pragma unroll
    for (int h2 = 0; h2 < 16; ++h2)
        rw[h2] = *(const float2*)(root2 + (q * 16 + h2) * 32 + 2 * m);
    float2 b2 = *(const float2*)(bias2 + 2 * m);
    for (int d = wave; d < N; d += nwaves) {
        int beg = start[d];
        int dg = deg[d];
        float invc = invtT[(size_t)d * 16 + m];     // lane r (<16) holds 1/cnt[r,d]
        float xr = x[(size_t)d * 64 + lane];
        float axA = 0.f, ayA = 0.f, axB = 0.f, ayB = 0.f;
        float axC = 0.f, ayC = 0.f, axD = 0.f, ayD = 0.f;
        for (int i = 0; i < dg; i += 64) {
            int v = esort[beg + min(i + lane, dg - 1)];
            int lim = min(64, dg - i);                    // wave-uniform
            for (int j = 0; j < lim; j += 16) {
                int cA = __shfl(v, j + q, 64);
                int cB = __shfl(v, j + 4 + q, 64);
                int cC = __shfl(v, j + 8 + q, 64);
                int cD = __shfl(v, j + 12 + q, 64);
                __hip_bfloat162 zA = z2[((size_t)(cA & 0xFFFFF) * 16 + (cA >> 20)) * 16 + m];
                __hip_bfloat162 zB = z2[((size_t)(cB & 0xFFFFF) * 16 + (cB >> 20)) * 16 + m];
                __hip_bfloat162 zC = z2[((size_t)(cC & 0xFFFFF) * 16 + (cC >> 20)) * 16 + m];
                __hip_bfloat162 zD = z2[((size_t)(cD & 0xFFFFF) * 16 + (cD >> 20)) * 16 + m];
                float fA = __shfl(invc, cA >> 20, 64) * ((j + q < lim) ? 1.f : 0.f);
                float fB = __shfl(invc, cB >> 20, 64) * ((j + 4 + q < lim) ? 1.f : 0.f);
                float fC = __shfl(invc, cC >> 20, 64) * ((j + 8 + q < lim) ? 1.f : 0.f);
                float fD = __shfl(invc, cD >> 20, 64) * ((j + 12 + q < lim) ? 1.f : 0.f);
                axA += __bfloat162float(zA.x) * fA; ayA += __bfloat162float(zA.y) * fA;
                axB += __bfloat162float(zB.x) * fB; ayB += __bfloat162float(zB.y) * fB;
                axC += __bfloat162float(zC.x) * fC; ayC += __bfloat162float(zC.y) * fC;
                axD += __bfloat162float(zD.x) * fD; ayD += __bfloat162float(zD.y) * fD;
            }
        }
        float tx = (axA + axB) + (axC + axD);
        float ty = (ayA + ayB) + (ayC + ayD);
        // root2 matvec from registers: this lane covers h = q*16 + h2
#pragma unroll
        for (int h2 = 0; h2 < 16; ++h2) {
            float xs = __shfl(xr, q * 16 + h2, 64);
            tx += xs * rw[h2].x;
            ty += xs * rw[h2].y;
        }
        tx += __shfl_xor(tx, 16, 64); ty += __shfl_xor(ty, 16, 64);
        tx += __shfl_xor(tx, 32, 64); ty += __shfl_xor(ty, 32, 64);
        if (q == 0) {
            float2 o;
            o.x = 1.0f / (1.0f + __expf(-(tx + b2.x)));
            o.y = 1.0f / (1.0f + __expf(-(ty + b2.y)));
            *(float2*)(out + (size_t)d * 32 + 2 * m) = o;
        }
    }
}

// ---------------- fallback path (small workspace): round-2 verified atomics ----
__global__ void count_kernel(const int* __restrict__ dst, const int* __restrict__ et,
                             int* __restrict__ cnt, int E, int N) {
    int i = blockIdx.x * blockDim.x + threadIdx.x;
    int stride = gridDim.x * blockDim.x;
    for (; i < E; i += stride) atomicAdd(&cnt[et[i] * N + dst[i]], 1);
}
__global__ void layer1_kernel(const int* __restrict__ src, const int* __restrict__ dst,
                              const int* __restrict__ et, const int* __restrict__ cnt,
                              const float* __restrict__ w1, float* __restrict__ h1,
                              int E, int N) {
    int lane = threadIdx.x & 63;
    int wave = (blockIdx.x * blockDim.x + threadIdx.x) >> 6;
    int nwaves = (gridDim.x * blockDim.x) >> 6;
    for (int e = wave; e < E; e += nwaves) {
        int r = et[e], s = src[e], d = dst[e];
        float inv = 1.0f / (float)cnt[r * N + d];
        atomicAdd(&h1[(size_t)d * 64 + lane], w1[((size_t)r * N + s) * 64 + lane] * inv);
    }
}
__global__ void x_kernel(float* __restrict__ h1, const float* __restrict__ root1,
                         const float* __restrict__ bias1, int NH) {
    int i = blockIdx.x * blockDim.x + threadIdx.x;
    int stride = gridDim.x * blockDim.x;
    for (; i < NH; i += stride) {
        float v = h1[i] + root1[i] + bias1[i & 63];
        h1[i] = v > 0.0f ? v : 0.0f;
    }
}
__global__ void layer2_kernel(const int* __restrict__ src, const int* __restrict__ dst,
                              const int* __restrict__ et, const int* __restrict__ cnt,
                              const float* __restrict__ x, const float* __restrict__ w2,
                              float* __restrict__ out, int E, int N) {
    int lane = threadIdx.x & 63;
    int l = lane & 31;
    int half = lane >> 5;
    int wave = (blockIdx.x * blockDim.x + threadIdx.x) >> 6;
    int nwaves = (gridDim.x * blockDim.x) >> 6;
    for (int e = wave; e < E; e += nwaves) {
        int r = et[e], s = src[e], d = dst[e];
        float inv = 1.0f / (float)cnt[r * N + d];
        float xv = x[(size_t)s * 64 + lane];
        const float* w2r = w2 + ((size_t)r * 64 + half * 32) * 32 + l;
        float acc = 0.0f;
#pragma unroll
        for (int i2 = 0; i2 < 32; ++i2) acc += __shfl(xv, half * 32 + i2, 64) * w2r[(size_t)i2 * 32];
        acc += __shfl_xor(acc, 32, 64);
        if (half == 0) atomicAdd(&out[(size_t)d * 32 + l], acc * inv);
    }
}
__global__ void final_kernel(float* __restrict__ out, const float* __restrict__ x,
                             const float* __restrict__ root2, const float* __restrict__ bias2,
                             int N) {
    int idx = blockIdx.x * blockDim.x + threadIdx.x;
    int stride = gridDim.x * blockDim.x;
    int total = N * 32;
    for (; idx < total; idx += stride) {
        int n = idx >> 5, l = idx & 31;
        float acc = out[idx] + bias2[l];
        const float* xr = x + (size_t)n * 64;
#pragma unroll
        for (int h = 0; h < 64; ++h) acc += xr[h] * root2[h * 32 + l];
        out[idx] = 1.0f / (1.0f + __expf(-acc));
    }
}

extern "C" void kernel_launch(void* const* d_in, const int* in_sizes, int n_in,
                              void* d_out, int out_size, void* d_ws, size_t ws_size,
                              hipStream_t stream) {
    const int*   edge_index = (const int*)d_in[0];   // [2, E]
    const int*   edge_type  = (const int*)d_in[1];   // [E]
    const float* w1         = (const float*)d_in[2]; // [R, N, 64]
    const float* root1      = (const float*)d_in[3]; // [N, 64]
    const float* bias1      = (const float*)d_in[4]; // [64]
    const float* w2         = (const float*)d_in[5]; // [R, 64, 32]
    const float* root2      = (const float*)d_in[6]; // [64, 32]
    const float* bias2      = (const float*)d_in[7]; // [32]
    float* out = (float*)d_out;

    int E = in_sizes[1];
    int H = in_sizes[4];            // 64
    int L = in_sizes[7];            // 32
    int N = in_sizes[3] / H;
    int R = in_sizes[5] / (H * L);  // <= 16

    const int* src = edge_index;
    const int* dst = edge_index + E;

    int nbkt = (N + BKT_SIZE - 1) / BKT_SIZE;   // 391 for N=50000
    int C = (E + NB1 - 1) / NB1;                // edges per phase-1 block

    // ws layout: [gh nbkt*NB1][gb nbkt*NB1][totals nbkt][bucketStart nbkt]
    //            [payB E][esort E][invtT N*16 f32][start N][deg N][x N*64][z N*16*32 bf16]
    size_t off_gh    = 0;
    size_t off_gb    = off_gh + (size_t)nbkt * NB1 * 4;
    size_t off_tot   = off_gb + (size_t)nbkt * NB1 * 4;
    size_t off_bs    = off_tot + (size_t)nbkt * 4;
    size_t off_payB  = off_bs + (size_t)nbkt * 4 + 64;
    size_t off_esort = off_payB + (size_t)E * 4;
    size_t off_invt  = off_esort + (size_t)E * 4;
    size_t off_start = off_invt + (size_t)N * 16 * 4;
    size_t off_deg   = off_start + (size_t)N * 4;
    size_t off_x     = off_deg + (size_t)N * 4;
    size_t off_z     = off_x + (size_t)N * H * 4;
    size_t need      = off_z + (size_t)N * 16 * L * 2;

    char* ws = (char*)d_ws;
    if (ws_size >= need && R <= 16 && nbkt <= 512 && N < (1 << 20)) {
        int*   gh    = (int*)(ws + off_gh);
        int*   gb    = (int*)(ws + off_gb);
        int*   tot   = (int*)(ws + off_tot);
        int*   bs    = (int*)(ws + off_bs);
        int*   payB  = (int*)(ws + off_payB);
        int*   esort = (int*)(ws + off_esort);
        float* invtT = (float*)(ws + off_invt);
        int*   start = (int*)(ws + off_start);
        int*   deg   = (int*)(ws + off_deg);
        float* x     = (float*)(ws + off_x);
        __hip_bfloat16* z = (__hip_bfloat16*)(ws + off_z);

        p1_hist      <<<NB1, 256, 0, stream>>>(dst, gh, E, C, nbkt);
        scan_a       <<<nbkt, NB1, 0, stream>>>(gh, gb, tot);
        scan_b       <<<1, 512, 0, stream>>>(tot, bs, nbkt);
        p1_scatter   <<<NB1, 256, 0, stream>>>(src, dst, edge_type, gb, bs, payB, E, C, nbkt);
        p2_sort      <<<nbkt, 256, 0, stream>>>(payB, bs, esort, start, deg, invtT, N, E, nbkt);
        layer1_gather<<<(N + 3) / 4, 256, 0, stream>>>(esort, start, deg, invtT, w1, root1, bias1, x, N);
        zgemm_kernel <<<2048, 256, 0, stream>>>(x, w2, z, N);
        layer2_gather<<<2048, 256, 0, stream>>>(esort, start, deg, invtT, z, x, root2, bias2, out, N);
    } else {
        // fallback: round-2 verified atomic path (needs ~16 MB)
        size_t cnt_bytes = (size_t)R * N * sizeof(int);
        int*   cnt = (int*)ws;
        float* h1  = (float*)(ws + cnt_bytes);
        hipMemsetAsync(cnt, 0, cnt_bytes + (size_t)N * H * sizeof(float), stream);
        hipMemsetAsync(out, 0, (size_t)N * L * sizeof(float), stream);
        count_kernel <<<2048, 256, 0, stream>>>(dst, edge_type, cnt, E, N);
        layer1_kernel<<<4096, 256, 0, stream>>>(src, dst, edge_type, cnt, w1, h1, E, N);
        x_kernel     <<<2048, 256, 0, stream>>>(h1, root1, bias1, N * H);
        layer2_kernel<<<4096, 256, 0, stream>>>(src, dst, edge_type, cnt, h1, w2, out, E, N);
        final_kernel <<<2048, 256, 0, stream>>>(out, h1, root2, bias2, N);
    }
}